// Round 17
// baseline (1944.059 us; speedup 1.0000x reference)
//
#include <hip/hip_runtime.h>
#include <math.h>

// LDGCNN forward: 4 EdgeConv blocks (knn K=20) + 1x1 conv block + global max pool + 3 FC.
// B=8, N=2048. Feature buffer X: (B, N, XS) rows, columns [pts(3)|f1(64)|f2(64)|f3(64)|f4(128)].
// XS=324 keeps rows 16B-aligned for float4 loads (column 323 is an unused pad).

constexpr int BB = 8;
constexpr int NN = 2048;
constexpr int KK = 20;
constexpr int CT = 323;
constexpr int XS = 324;
constexpr float NEGS = 0.2f;

__device__ __forceinline__ float lrelu(float v) { return v > 0.0f ? v : NEGS * v; }

__device__ __forceinline__ void atomicMaxF(float* addr, float v) {
    if (v >= 0.0f) atomicMax((int*)addr, __float_as_int(v));
    else           atomicMin((unsigned int*)addr, __float_as_uint(v));
}

// ---- transpose x (B,3,N) -> X[:, :, 0:3] -------------------------------------------------
__global__ void k_transpose(const float* __restrict__ x, float* __restrict__ X) {
    int i = blockIdx.x * blockDim.x + threadIdx.x;
    if (i >= BB * 3 * NN) return;
    int n = i % NN;
    int c = (i / NN) % 3;
    int b = i / (3 * NN);
    X[(size_t)(b * NN + n) * XS + c] = x[i];
}

// ---- squared norms over prefix C ---------------------------------------------------------
__global__ void k_sq(const float* __restrict__ X, float* __restrict__ sq, int C) {
    int i = blockIdx.x * blockDim.x + threadIdx.x;
    if (i >= BB * NN) return;
    const float* row = X + (size_t)i * XS;
    float s = 0.f;
    for (int c = 0; c < C; ++c) s += row[c] * row[c];
    sq[i] = s;
}

// ---- dist[b][n][m] = max(sq_n + sq_m - 2*dot, 0) — SYMMETRIC: only tiles ti>=tj ----------
// 128x128 tile, 8x8 per thread. Off-diagonal blocks write direct + mirrored (LDS transpose).
constexpr int TM = 128;
__global__ __launch_bounds__(256) void k_dist(const float* __restrict__ X,
                                              const float* __restrict__ sq,
                                              float* __restrict__ dist, int C) {
    int b = blockIdx.z;
    int blk = blockIdx.x;                 // 0..135 -> (ti, tj), ti >= tj
    int ti = (int)((sqrtf(8.0f * blk + 1.0f) - 1.0f) * 0.5f);
    while ((ti + 1) * (ti + 2) / 2 <= blk) ++ti;
    while (ti * (ti + 1) / 2 > blk) --ti;
    int tj = blk - ti * (ti + 1) / 2;
    int m0 = ti * TM;                     // col tile
    int n0 = tj * TM;                     // row tile
    __shared__ float smem[4352];          // 17 KB: staging (16 KB) / transpose T[32][129]
    float* AsB = smem;                    // As[16][TM]
    float* BsB = smem + 2048;             // Bs[16][TM]
    int tid = threadIdx.x;
    int tx = tid & 15;        // cols: m0 + tx + 16*j
    int ty = tid >> 4;        // rows: n0 + ty*8 + i
    float acc[8][8] = {};
    const float* Xb = X + (size_t)b * NN * XS;
    int sr = tid & 127;       // staging row
    int sc0 = (tid >> 7) * 8; // staging channel half (0 or 8)
    for (int c0 = 0; c0 < C; c0 += 16) {
        const float* arow = Xb + (size_t)(n0 + sr) * XS + c0 + sc0;
        const float* brow = Xb + (size_t)(m0 + sr) * XS + c0 + sc0;
        float4 a0 = *(const float4*)(arow);
        float4 a1 = *(const float4*)(arow + 4);
        float4 b0 = *(const float4*)(brow);
        float4 b1 = *(const float4*)(brow + 4);
        float av[8] = {a0.x, a0.y, a0.z, a0.w, a1.x, a1.y, a1.z, a1.w};
        float bv8[8] = {b0.x, b0.y, b0.z, b0.w, b1.x, b1.y, b1.z, b1.w};
#pragma unroll
        for (int i = 0; i < 8; ++i) {
            bool inr = (c0 + sc0 + i) < C;
            AsB[(sc0 + i) * TM + sr] = inr ? av[i] : 0.f;
            BsB[(sc0 + i) * TM + sr] = inr ? bv8[i] : 0.f;
        }
        __syncthreads();
#pragma unroll
        for (int cc = 0; cc < 16; ++cc) {
            float4 a0r = *(const float4*)&AsB[cc * TM + ty * 8];
            float4 a1r = *(const float4*)&AsB[cc * TM + ty * 8 + 4];
            float a[8] = {a0r.x, a0r.y, a0r.z, a0r.w, a1r.x, a1r.y, a1r.z, a1r.w};
            float bv[8];
#pragma unroll
            for (int j = 0; j < 8; ++j) bv[j] = BsB[cc * TM + tx + 16 * j];
#pragma unroll
            for (int i = 0; i < 8; ++i)
#pragma unroll
                for (int j = 0; j < 8; ++j)
                    acc[i][j] = fmaf(a[i], bv[j], acc[i][j]);
        }
        __syncthreads();
    }
    const float* sqb = sq + b * NN;
    float* db = dist + (size_t)b * NN * NN;
    float sm[8];
#pragma unroll
    for (int j = 0; j < 8; ++j) sm[j] = sqb[m0 + tx + 16 * j];
#pragma unroll
    for (int i = 0; i < 8; ++i) {
        int n = n0 + ty * 8 + i;
        float sn = sqb[n];
#pragma unroll
        for (int j = 0; j < 8; ++j) {
            float d = fmaxf(sn + sm[j] - 2.f * acc[i][j], 0.f);
            acc[i][j] = d;                                   // keep for mirror
            db[(size_t)n * NN + m0 + tx + 16 * j] = d;
        }
    }
    if (ti != tj) {
        // mirrored tile: rows m0.., cols n0.. — 4 passes of 32 m-rows via LDS transpose
        float* T = smem;                  // [32][129]
        int r = tid >> 3;                 // 0..31
        int c0 = (tid & 7) * 16;          // 0..112
#pragma unroll
        for (int p = 0; p < 4; ++p) {
            __syncthreads();              // protect staging/previous pass reads
#pragma unroll
            for (int jj = 0; jj < 2; ++jj) {
                int j = 2 * p + jj;       // m_local = 32p + tx + 16jj
#pragma unroll
                for (int i = 0; i < 8; ++i)
                    T[(tx + 16 * jj) * 129 + ty * 8 + i] = acc[i][j];
            }
            __syncthreads();
            float v[16];
#pragma unroll
            for (int k = 0; k < 16; ++k) v[k] = T[r * 129 + c0 + k];
            float* dst = db + (size_t)(m0 + 32 * p + r) * NN + n0 + c0;
#pragma unroll
            for (int k = 0; k < 4; ++k)
                *(float4*)(dst + 4 * k) = make_float4(v[4 * k], v[4 * k + 1],
                                                      v[4 * k + 2], v[4 * k + 3]);
        }
    }
}

// ---- Batcher odd-even mergesort network, N=16, fully unrolled (registers) ----------------
__device__ __forceinline__ void sortnet16(unsigned long long* k) {
#pragma unroll
    for (int p = 1; p < 16; p <<= 1) {
#pragma unroll
        for (int q = p; q >= 1; q >>= 1) {
#pragma unroll
            for (int j = q % p; j + q < 16; j += 2 * q) {
#pragma unroll
                for (int i = 0; i < q; ++i) {
                    int a = j + i, bx = j + i + q;
                    if (bx < 16 && (a / (2 * p)) == (bx / (2 * p))) {
                        unsigned long long ka = k[a], kb = k[bx];
                        bool sw = kb < ka;
                        k[a]  = sw ? kb : ka;
                        k[bx] = sw ? ka : kb;
                    }
                }
            }
        }
    }
}

// ---- top-K smallest per row: key = (bits(d)<<11)|m; ties -> lower m (lax.top_k) ----------
__global__ __launch_bounds__(128) void k_select(const float* __restrict__ dist,
                                                int* __restrict__ idx) {
    int bn = blockIdx.x;   // b*NN + n
    int tid = threadIdx.x;
    int wv = tid >> 6;
    int lane = tid & 63;
    const float* drow = dist + (size_t)bn * NN;
    int m0 = wv * 1024 + lane * 16;
    unsigned long long k[16];
#pragma unroll
    for (int i = 0; i < 4; ++i) {
        float4 v = *(const float4*)(drow + m0 + 4 * i);
        k[4 * i + 0] = ((unsigned long long)__float_as_uint(v.x) << 11) | (unsigned)(m0 + 4 * i + 0);
        k[4 * i + 1] = ((unsigned long long)__float_as_uint(v.y) << 11) | (unsigned)(m0 + 4 * i + 1);
        k[4 * i + 2] = ((unsigned long long)__float_as_uint(v.z) << 11) | (unsigned)(m0 + 4 * i + 2);
        k[4 * i + 3] = ((unsigned long long)__float_as_uint(v.w) << 11) | (unsigned)(m0 + 4 * i + 3);
    }
    sortnet16(k);
    __shared__ unsigned long long wl[2 * KK];
    for (int kk = 0; kk < KK; ++kk) {
        unsigned long long g = k[0];
#pragma unroll
        for (int s = 1; s < 64; s <<= 1) {
            unsigned long long o = (unsigned long long)__shfl_xor((long long)g, s, 64);
            if (o < g) g = o;
        }
        bool win = (k[0] == g);
#pragma unroll
        for (int i = 0; i < 15; ++i) k[i] = win ? k[i + 1] : k[i];
        k[15] = win ? ~0ull : k[15];
        if (lane == 0) wl[wv * KK + kk] = g;
    }
    __syncthreads();
    if (wv == 0) {
        unsigned long long mk = (lane < 2 * KK) ? wl[lane] : ~0ull;
        int* orow = idx + (size_t)bn * KK;
        for (int kk = 0; kk < KK; ++kk) {
            unsigned long long g = mk;
#pragma unroll
            for (int s = 1; s < 64; s <<= 1) {
                unsigned long long o = (unsigned long long)__shfl_xor((long long)g, s, 64);
                if (o < g) g = o;
            }
            if (mk == g) mk = ~0ull;
            if (lane == 0) orow[kk] = (int)(g & 2047u);
        }
    }
}

// ---- weight prep, float4-packed per 4-channel chunk (zero-padded to NC4 chunks) ----------
__global__ void k_prepw(const float* __restrict__ W, float4* __restrict__ Wa4,
                        float4* __restrict__ Wd4, int C, int NC4, int Cout) {
    int j = blockIdx.x * blockDim.x + threadIdx.x;
    if (j >= NC4 * Cout) return;
    int chunk = j / Cout, o = j % Cout;
    float wa[4], wd[4];
#pragma unroll
    for (int i = 0; i < 4; ++i) {
        int c = 4 * chunk + i;
        if (c < C) {
            wa[i] = W[(size_t)o * 2 * C + c];
            wd[i] = W[(size_t)o * 2 * C + C + c] - wa[i];
        } else { wa[i] = 0.f; wd[i] = 0.f; }
    }
    Wa4[j] = make_float4(wa[0], wa[1], wa[2], wa[3]);
    Wd4[j] = make_float4(wd[0], wd[1], wd[2], wd[3]);
}

// ---- EdgeConv: P points/block, MO outputs/thread, NPASS channel passes. ------------------
// Mo=2 inner loop (proven optimum); P=8 doubles waves/CU (latency hiding for the scattered
// neighbor gather, the current gate) and halves per-weight L2 traffic. Padded LDS strides
// keep multi-address broadcast reads on disjoint bank quads. launch_bounds(...,2) blocks
// the R13 spill. Pad chunks carry zero weights.
template <int NC4, int COUT, int P, int NPASS, int MO>
__global__ __launch_bounds__(P * (COUT / MO), 2)
void k_conv(const float* __restrict__ X, const int* __restrict__ idx,
            const float4* __restrict__ Wa4, const float4* __restrict__ Wd4,
            const float* __restrict__ scale, const float* __restrict__ bias,
            int outoff, float* __restrict__ Xout) {
    constexpr int NCP = NC4 / NPASS;      // chunks per pass (exact by construction)
    constexpr int OS = COUT / MO;         // threads per point; output stride
    constexpr int NTHR = P * OS;
    constexpr int PADN = KK * NCP + 1;    // padded nbr stride (float4) per point
    constexpr int PADC = NCP + 1;         // padded ctr stride
    int bn0 = blockIdx.x * P;             // P consecutive points, same batch
    int b = bn0 >> 11;                    // NN = 2048
    __shared__ float4 ctr4[P * PADC];
    __shared__ float4 nbr4[P * PADN];
    __shared__ int sIdx[P * KK];
    int tid = threadIdx.x;
    for (int j = tid; j < P * KK; j += NTHR) sIdx[j] = idx[(size_t)bn0 * KK + j];
    __syncthreads();
    int o = tid & (OS - 1);
    int p = tid / OS;
    float bacc[MO];
    float acc[MO][KK];
#pragma unroll
    for (int m = 0; m < MO; ++m) {
        bacc[m] = 0.f;
#pragma unroll
        for (int kk = 0; kk < KK; ++kk) acc[m][kk] = 0.f;
    }
#pragma unroll
    for (int q = 0; q < NPASS; ++q) {
        int cbase = q * NCP;
        // stage ctr chunks
        for (int j = tid; j < P * NCP; j += NTHR) {
            int pp = j / NCP, c = j - pp * NCP;
            ctr4[pp * PADC + c] = *(const float4*)(X + (size_t)(bn0 + pp) * XS + 4 * (cbase + c));
        }
        // stage nbr chunks (padded layout)
        for (int j = tid; j < P * KK * NCP; j += NTHR) {
            int pk = j / NCP, c = j - pk * NCP;
            int pp = pk / KK, kk2 = pk - pp * KK;
            nbr4[pp * PADN + kk2 * NCP + c] =
                *(const float4*)(X + (size_t)(b * NN + sIdx[pk]) * XS + 4 * (cbase + c));
        }
        __syncthreads();
        const float4* cp = ctr4 + p * PADC;
        const float4* np = nbr4 + p * PADN;
#pragma unroll 2
        for (int ch = 0; ch < NCP; ++ch) {
            int gch = cbase + ch;
            float4 wa[MO], wd[MO];
#pragma unroll
            for (int m = 0; m < MO; ++m) {
                wa[m] = Wa4[(size_t)gch * COUT + o + m * OS];
                wd[m] = Wd4[(size_t)gch * COUT + o + m * OS];
            }
            float4 cv = cp[ch];
#pragma unroll
            for (int m = 0; m < MO; ++m) {
                bacc[m] = fmaf(cv.x, wd[m].x, bacc[m]);
                bacc[m] = fmaf(cv.y, wd[m].y, bacc[m]);
                bacc[m] = fmaf(cv.z, wd[m].z, bacc[m]);
                bacc[m] = fmaf(cv.w, wd[m].w, bacc[m]);
            }
#pragma unroll
            for (int kk = 0; kk < KK; ++kk) {
                float4 nv = np[kk * NCP + ch];
#pragma unroll
                for (int m = 0; m < MO; ++m) {
                    acc[m][kk] = fmaf(nv.x, wa[m].x, acc[m][kk]);
                    acc[m][kk] = fmaf(nv.y, wa[m].y, acc[m][kk]);
                    acc[m][kk] = fmaf(nv.z, wa[m].z, acc[m][kk]);
                    acc[m][kk] = fmaf(nv.w, wa[m].w, acc[m][kk]);
                }
            }
        }
        if (q + 1 < NPASS) __syncthreads();   // before next pass overwrites LDS
    }
    float* orow = Xout + (size_t)(bn0 + p) * XS + outoff;
#pragma unroll
    for (int m = 0; m < MO; ++m) {
        int oo = o + m * OS;
        float s = scale[oo], bi = bias[oo];
        float mx = -INFINITY;
#pragma unroll
        for (int kk = 0; kk < KK; ++kk) mx = fmaxf(mx, lrelu((bacc[m] + acc[m][kk]) * s + bi));
        orow[oo] = mx;
    }
}

// ---- W5 transpose to [c][o], zero-padded to XS rows (row 323 = 0 so X pad is harmless) ---
__global__ void k_prepw5(const float* __restrict__ W5, float* __restrict__ W5T) {
    int j = blockIdx.x * blockDim.x + threadIdx.x;
    if (j >= XS * 1024) return;
    int c = j / 1024, o = j % 1024;
    W5T[j] = (c < CT) ? W5[(size_t)o * CT + c] : 0.f;
}

__global__ void k_init_gfeat(float* __restrict__ gfeat) {
    int i = blockIdx.x * blockDim.x + threadIdx.x;
    if (i < BB * 1024) gfeat[i] = -INFINITY;
}

// ---- block5: g = lrelu((X . W5^T)*s5+b5), atomic max over n into gfeat -------------------
constexpr int RB = 8;
constexpr int X4S = XS / 4;   // 81 float4 per row
__global__ __launch_bounds__(256) void k_stage5(const float* __restrict__ X,
                                                const float* __restrict__ W5T,
                                                const float* __restrict__ s5,
                                                const float* __restrict__ b5,
                                                float* __restrict__ gfeat) {
    int blk = blockIdx.x;
    int b = blk / (NN / RB);
    int n0 = (blk % (NN / RB)) * RB;
    __shared__ float4 rows4[RB][X4S];
    int tid = threadIdx.x;
    const float4* X4 = (const float4*)X;
    for (int j = tid; j < RB * X4S; j += 256) {
        int r = j / X4S, c = j - r * X4S;
        rows4[r][c] = X4[(size_t)(b * NN + n0 + r) * X4S + c];
    }
    __syncthreads();
    const float4* W5T4 = (const float4*)W5T;   // [XS][256] float4 per row
    float acc[RB][4] = {};
    for (int c4 = 0; c4 < X4S; ++c4) {
        float4 w0 = W5T4[(size_t)(4 * c4 + 0) * 256 + tid];
        float4 w1 = W5T4[(size_t)(4 * c4 + 1) * 256 + tid];
        float4 w2 = W5T4[(size_t)(4 * c4 + 2) * 256 + tid];
        float4 w3 = W5T4[(size_t)(4 * c4 + 3) * 256 + tid];
#pragma unroll
        for (int r = 0; r < RB; ++r) {
            float4 a = rows4[r][c4];
            acc[r][0] = fmaf(a.x, w0.x, acc[r][0]);
            acc[r][1] = fmaf(a.x, w0.y, acc[r][1]);
            acc[r][2] = fmaf(a.x, w0.z, acc[r][2]);
            acc[r][3] = fmaf(a.x, w0.w, acc[r][3]);
            acc[r][0] = fmaf(a.y, w1.x, acc[r][0]);
            acc[r][1] = fmaf(a.y, w1.y, acc[r][1]);
            acc[r][2] = fmaf(a.y, w1.z, acc[r][2]);
            acc[r][3] = fmaf(a.y, w1.w, acc[r][3]);
            acc[r][0] = fmaf(a.z, w2.x, acc[r][0]);
            acc[r][1] = fmaf(a.z, w2.y, acc[r][1]);
            acc[r][2] = fmaf(a.z, w2.z, acc[r][2]);
            acc[r][3] = fmaf(a.z, w2.w, acc[r][3]);
            acc[r][0] = fmaf(a.w, w3.x, acc[r][0]);
            acc[r][1] = fmaf(a.w, w3.y, acc[r][1]);
            acc[r][2] = fmaf(a.w, w3.z, acc[r][2]);
            acc[r][3] = fmaf(a.w, w3.w, acc[r][3]);
        }
    }
    int o0 = tid * 4;
#pragma unroll
    for (int i = 0; i < 4; ++i) {
        int o = o0 + i;
        float s = s5[o], bbv = b5[o];
        float mx = -INFINITY;
#pragma unroll
        for (int r = 0; r < RB; ++r) {
            float v = lrelu(acc[r][i] * s + bbv);
            mx = fmaxf(v, mx);
        }
        atomicMaxF(&gfeat[b * 1024 + o], mx);
    }
}

// ---- FC head -----------------------------------------------------------------------------
__global__ void k_fc1(const float* __restrict__ gfeat, const float* __restrict__ fW1,
                      const float* __restrict__ fb1, const float* __restrict__ fs1,
                      const float* __restrict__ fB1, float* __restrict__ h1) {
    int b = blockIdx.x;
    __shared__ float g[1024];
    int tid = threadIdx.x;
    for (int j = tid; j < 1024; j += 256) g[j] = gfeat[b * 1024 + j];
    __syncthreads();
    for (int o = tid; o < 512; o += 256) {
        const float* wr = fW1 + (size_t)o * 1024;
        float acc = 0.f;
        for (int c = 0; c < 1024; ++c) acc = fmaf(g[c], wr[c], acc);
        h1[b * 512 + o] = lrelu((acc + fb1[o]) * fs1[o] + fB1[o]);
    }
}

__global__ void k_fc2(const float* __restrict__ h1, const float* __restrict__ fW2,
                      const float* __restrict__ fb2, const float* __restrict__ fs2,
                      const float* __restrict__ fB2, float* __restrict__ h2) {
    int b = blockIdx.x;
    __shared__ float g[512];
    int tid = threadIdx.x;
    for (int j = tid; j < 512; j += 256) g[j] = h1[b * 512 + j];
    __syncthreads();
    int o = tid;
    const float* wr = fW2 + (size_t)o * 512;
    float acc = 0.f;
    for (int c = 0; c < 512; ++c) acc = fmaf(g[c], wr[c], acc);
    h2[b * 256 + o] = lrelu((acc + fb2[o]) * fs2[o] + fB2[o]);
}

__global__ void k_fc3(const float* __restrict__ h2, const float* __restrict__ fW3,
                      const float* __restrict__ fb3, float* __restrict__ logits) {
    int b = blockIdx.x;
    __shared__ float g[256];
    int tid = threadIdx.x;
    for (int j = tid; j < 256; j += 64) g[j] = h2[b * 256 + j];
    __syncthreads();
    if (tid < 40) {
        const float* wr = fW3 + (size_t)tid * 256;
        float acc = 0.f;
        for (int c = 0; c < 256; ++c) acc = fmaf(g[c], wr[c], acc);
        logits[b * 40 + tid] = acc + fb3[tid];
    }
}

extern "C" void kernel_launch(void* const* d_in, const int* in_sizes, int n_in,
                              void* d_out, int out_size, void* d_ws, size_t ws_size,
                              hipStream_t stream) {
    const float* x   = (const float*)d_in[0];
    const float* W1  = (const float*)d_in[1];
    const float* s1  = (const float*)d_in[2];
    const float* b1  = (const float*)d_in[3];
    const float* W2  = (const float*)d_in[4];
    const float* s2  = (const float*)d_in[5];
    const float* b2  = (const float*)d_in[6];
    const float* W3  = (const float*)d_in[7];
    const float* s3  = (const float*)d_in[8];
    const float* b3  = (const float*)d_in[9];
    const float* W4  = (const float*)d_in[10];
    const float* s4  = (const float*)d_in[11];
    const float* b4  = (const float*)d_in[12];
    const float* W5  = (const float*)d_in[13];
    const float* s5  = (const float*)d_in[14];
    const float* b5  = (const float*)d_in[15];
    const float* fW1 = (const float*)d_in[16];
    const float* fb1 = (const float*)d_in[17];
    const float* fs1 = (const float*)d_in[18];
    const float* fB1 = (const float*)d_in[19];
    const float* fW2 = (const float*)d_in[20];
    const float* fb2 = (const float*)d_in[21];
    const float* fs2 = (const float*)d_in[22];
    const float* fB2 = (const float*)d_in[23];
    const float* fW3 = (const float*)d_in[24];
    const float* fb3 = (const float*)d_in[25];

    float* out    = (float*)d_out;
    float* logits = out;          // 8*40
    float* gfeat  = out + 320;    // 8*1024

    char* ws = (char*)d_ws;
    size_t off = 0;
    auto alloc = [&](size_t bytes) -> void* {
        void* p = ws + off;
        off += (bytes + 255) & ~(size_t)255;
        return p;
    };
    float* X    = (float*)alloc((size_t)BB * NN * XS * 4);      // 21.2 MB
    float* sq   = (float*)alloc((size_t)BB * NN * 4);
    float* dist = (float*)alloc((size_t)BB * NN * NN * 4);      // 134 MB
    int*   idx  = (int*)  alloc((size_t)BB * NN * KK * 4);
    float4* Wa4 = (float4*)alloc((size_t)52 * 128 * 16);
    float4* Wd4 = (float4*)alloc((size_t)52 * 128 * 16);
    float* W5T  = (float*)alloc((size_t)XS * 1024 * 4);
    float* h1   = (float*)alloc((size_t)BB * 512 * 4);
    float* h2   = (float*)alloc((size_t)BB * 256 * 4);
    (void)ws_size; (void)in_sizes; (void)n_in; (void)out_size;

    k_transpose<<<(BB * 3 * NN + 255) / 256, 256, 0, stream>>>(x, X);

    const int Cs[4]    = {3, 67, 131, 195};
    const int Couts[4] = {64, 64, 64, 128};
    const int offs[4]  = {3, 67, 131, 195};
    const int NC4s[4]  = {1, 18, 36, 52};   // padded chunk counts (NPASS-divisible)
    const float* Ws[4] = {W1, W2, W3, W4};
    const float* ss[4] = {s1, s2, s3, s4};
    const float* bs[4] = {b1, b2, b3, b4};

    constexpr int NT = NN / TM;                 // 16 tiles per dim
    constexpr int NBLK = NT * (NT + 1) / 2;     // 136 lower-triangle tiles
    for (int st = 0; st < 4; ++st) {
        int C = Cs[st], Cout = Couts[st];
        int NC4 = NC4s[st];
        k_sq<<<(BB * NN + 255) / 256, 256, 0, stream>>>(X, sq, C);
        dim3 dg(NBLK, 1, BB);
        k_dist<<<dg, 256, 0, stream>>>(X, sq, dist, C);
        k_select<<<BB * NN, 128, 0, stream>>>(dist, idx);
        k_prepw<<<(NC4 * Cout + 255) / 256, 256, 0, stream>>>(Ws[st], Wa4, Wd4, C, NC4, Cout);
        switch (st) {
            // <NC4, COUT, P, NPASS, MO>
            case 0: k_conv<1, 64, 4, 1, 2><<<BB * NN / 4, 128, 0, stream>>>(X, idx, Wa4, Wd4, ss[st], bs[st], offs[st], X); break;
            case 1: k_conv<18, 64, 8, 2, 2><<<BB * NN / 8, 256, 0, stream>>>(X, idx, Wa4, Wd4, ss[st], bs[st], offs[st], X); break;
            case 2: k_conv<36, 64, 8, 4, 2><<<BB * NN / 8, 256, 0, stream>>>(X, idx, Wa4, Wd4, ss[st], bs[st], offs[st], X); break;
            case 3: k_conv<52, 128, 8, 4, 2><<<BB * NN / 8, 512, 0, stream>>>(X, idx, Wa4, Wd4, ss[st], bs[st], offs[st], X); break;
        }
    }

    k_prepw5<<<(XS * 1024 + 255) / 256, 256, 0, stream>>>(W5, W5T);
    k_init_gfeat<<<(BB * 1024 + 255) / 256, 256, 0, stream>>>(gfeat);
    k_stage5<<<BB * (NN / RB), 256, 0, stream>>>(X, W5T, s5, b5, gfeat);
    k_fc1<<<BB, 256, 0, stream>>>(gfeat, fW1, fb1, fs1, fB1, h1);
    k_fc2<<<BB, 256, 0, stream>>>(h1, fW2, fb2, fs2, fB2, h2);
    k_fc3<<<BB, 64, 0, stream>>>(h2, fW3, fb3, logits);
}

// Round 18
// 1822.426 us; speedup vs baseline: 1.0667x; 1.0667x over previous
//
#include <hip/hip_runtime.h>
#include <math.h>

// LDGCNN forward: 4 EdgeConv blocks (knn K=20) + 1x1 conv block + global max pool + 3 FC.
// B=8, N=2048. Feature buffer X: (B, N, XS) rows, columns [pts(3)|f1(64)|f2(64)|f3(64)|f4(128)].
// XS=324 keeps rows 16B-aligned for float4 loads (column 323 is an unused pad).

constexpr int BB = 8;
constexpr int NN = 2048;
constexpr int KK = 20;
constexpr int CT = 323;
constexpr int XS = 324;
constexpr float NEGS = 0.2f;

__device__ __forceinline__ float lrelu(float v) { return v > 0.0f ? v : NEGS * v; }

__device__ __forceinline__ void atomicMaxF(float* addr, float v) {
    if (v >= 0.0f) atomicMax((int*)addr, __float_as_int(v));
    else           atomicMin((unsigned int*)addr, __float_as_uint(v));
}

// ---- transpose x (B,3,N) -> X[:, :, 0:3] -------------------------------------------------
__global__ void k_transpose(const float* __restrict__ x, float* __restrict__ X) {
    int i = blockIdx.x * blockDim.x + threadIdx.x;
    if (i >= BB * 3 * NN) return;
    int n = i % NN;
    int c = (i / NN) % 3;
    int b = i / (3 * NN);
    X[(size_t)(b * NN + n) * XS + c] = x[i];
}

// ---- squared norms over prefix C ---------------------------------------------------------
__global__ void k_sq(const float* __restrict__ X, float* __restrict__ sq, int C) {
    int i = blockIdx.x * blockDim.x + threadIdx.x;
    if (i >= BB * NN) return;
    const float* row = X + (size_t)i * XS;
    float s = 0.f;
    for (int c = 0; c < C; ++c) s += row[c] * row[c];
    sq[i] = s;
}

// ---- dist[b][n][m] = max(sq_n + sq_m - 2*dot, 0) — SYMMETRIC: only tiles ti>=tj ----------
// 128x128 tile, 8x8 per thread. Off-diagonal blocks write direct + mirrored (LDS transpose).
constexpr int TM = 128;
__global__ __launch_bounds__(256) void k_dist(const float* __restrict__ X,
                                              const float* __restrict__ sq,
                                              float* __restrict__ dist, int C) {
    int b = blockIdx.z;
    int blk = blockIdx.x;                 // 0..135 -> (ti, tj), ti >= tj
    int ti = (int)((sqrtf(8.0f * blk + 1.0f) - 1.0f) * 0.5f);
    while ((ti + 1) * (ti + 2) / 2 <= blk) ++ti;
    while (ti * (ti + 1) / 2 > blk) --ti;
    int tj = blk - ti * (ti + 1) / 2;
    int m0 = ti * TM;                     // col tile
    int n0 = tj * TM;                     // row tile
    __shared__ float smem[4352];          // 17 KB: staging (16 KB) / transpose T[32][129]
    float* AsB = smem;                    // As[16][TM]
    float* BsB = smem + 2048;             // Bs[16][TM]
    int tid = threadIdx.x;
    int tx = tid & 15;        // cols: m0 + tx + 16*j
    int ty = tid >> 4;        // rows: n0 + ty*8 + i
    float acc[8][8] = {};
    const float* Xb = X + (size_t)b * NN * XS;
    int sr = tid & 127;       // staging row
    int sc0 = (tid >> 7) * 8; // staging channel half (0 or 8)
    for (int c0 = 0; c0 < C; c0 += 16) {
        const float* arow = Xb + (size_t)(n0 + sr) * XS + c0 + sc0;
        const float* brow = Xb + (size_t)(m0 + sr) * XS + c0 + sc0;
        float4 a0 = *(const float4*)(arow);
        float4 a1 = *(const float4*)(arow + 4);
        float4 b0 = *(const float4*)(brow);
        float4 b1 = *(const float4*)(brow + 4);
        float av[8] = {a0.x, a0.y, a0.z, a0.w, a1.x, a1.y, a1.z, a1.w};
        float bv8[8] = {b0.x, b0.y, b0.z, b0.w, b1.x, b1.y, b1.z, b1.w};
#pragma unroll
        for (int i = 0; i < 8; ++i) {
            bool inr = (c0 + sc0 + i) < C;
            AsB[(sc0 + i) * TM + sr] = inr ? av[i] : 0.f;
            BsB[(sc0 + i) * TM + sr] = inr ? bv8[i] : 0.f;
        }
        __syncthreads();
#pragma unroll
        for (int cc = 0; cc < 16; ++cc) {
            float4 a0r = *(const float4*)&AsB[cc * TM + ty * 8];
            float4 a1r = *(const float4*)&AsB[cc * TM + ty * 8 + 4];
            float a[8] = {a0r.x, a0r.y, a0r.z, a0r.w, a1r.x, a1r.y, a1r.z, a1r.w};
            float bv[8];
#pragma unroll
            for (int j = 0; j < 8; ++j) bv[j] = BsB[cc * TM + tx + 16 * j];
#pragma unroll
            for (int i = 0; i < 8; ++i)
#pragma unroll
                for (int j = 0; j < 8; ++j)
                    acc[i][j] = fmaf(a[i], bv[j], acc[i][j]);
        }
        __syncthreads();
    }
    const float* sqb = sq + b * NN;
    float* db = dist + (size_t)b * NN * NN;
    float sm[8];
#pragma unroll
    for (int j = 0; j < 8; ++j) sm[j] = sqb[m0 + tx + 16 * j];
#pragma unroll
    for (int i = 0; i < 8; ++i) {
        int n = n0 + ty * 8 + i;
        float sn = sqb[n];
#pragma unroll
        for (int j = 0; j < 8; ++j) {
            float d = fmaxf(sn + sm[j] - 2.f * acc[i][j], 0.f);
            acc[i][j] = d;                                   // keep for mirror
            db[(size_t)n * NN + m0 + tx + 16 * j] = d;
        }
    }
    if (ti != tj) {
        // mirrored tile: rows m0.., cols n0.. — 4 passes of 32 m-rows via LDS transpose
        float* T = smem;                  // [32][129]
        int r = tid >> 3;                 // 0..31
        int c0 = (tid & 7) * 16;          // 0..112
#pragma unroll
        for (int p = 0; p < 4; ++p) {
            __syncthreads();              // protect staging/previous pass reads
#pragma unroll
            for (int jj = 0; jj < 2; ++jj) {
                int j = 2 * p + jj;       // m_local = 32p + tx + 16jj
#pragma unroll
                for (int i = 0; i < 8; ++i)
                    T[(tx + 16 * jj) * 129 + ty * 8 + i] = acc[i][j];
            }
            __syncthreads();
            float v[16];
#pragma unroll
            for (int k = 0; k < 16; ++k) v[k] = T[r * 129 + c0 + k];
            float* dst = db + (size_t)(m0 + 32 * p + r) * NN + n0 + c0;
#pragma unroll
            for (int k = 0; k < 4; ++k)
                *(float4*)(dst + 4 * k) = make_float4(v[4 * k], v[4 * k + 1],
                                                      v[4 * k + 2], v[4 * k + 3]);
        }
    }
}

// ---- Batcher odd-even mergesort network, N=16, fully unrolled (registers) ----------------
__device__ __forceinline__ void sortnet16(unsigned long long* k) {
#pragma unroll
    for (int p = 1; p < 16; p <<= 1) {
#pragma unroll
        for (int q = p; q >= 1; q >>= 1) {
#pragma unroll
            for (int j = q % p; j + q < 16; j += 2 * q) {
#pragma unroll
                for (int i = 0; i < q; ++i) {
                    int a = j + i, bx = j + i + q;
                    if (bx < 16 && (a / (2 * p)) == (bx / (2 * p))) {
                        unsigned long long ka = k[a], kb = k[bx];
                        bool sw = kb < ka;
                        k[a]  = sw ? kb : ka;
                        k[bx] = sw ? ka : kb;
                    }
                }
            }
        }
    }
}

// ---- top-K smallest per row: key = (bits(d)<<11)|m; ties -> lower m (lax.top_k) ----------
__global__ __launch_bounds__(128) void k_select(const float* __restrict__ dist,
                                                int* __restrict__ idx) {
    int bn = blockIdx.x;   // b*NN + n
    int tid = threadIdx.x;
    int wv = tid >> 6;
    int lane = tid & 63;
    const float* drow = dist + (size_t)bn * NN;
    int m0 = wv * 1024 + lane * 16;
    unsigned long long k[16];
#pragma unroll
    for (int i = 0; i < 4; ++i) {
        float4 v = *(const float4*)(drow + m0 + 4 * i);
        k[4 * i + 0] = ((unsigned long long)__float_as_uint(v.x) << 11) | (unsigned)(m0 + 4 * i + 0);
        k[4 * i + 1] = ((unsigned long long)__float_as_uint(v.y) << 11) | (unsigned)(m0 + 4 * i + 1);
        k[4 * i + 2] = ((unsigned long long)__float_as_uint(v.z) << 11) | (unsigned)(m0 + 4 * i + 2);
        k[4 * i + 3] = ((unsigned long long)__float_as_uint(v.w) << 11) | (unsigned)(m0 + 4 * i + 3);
    }
    sortnet16(k);
    __shared__ unsigned long long wl[2 * KK];
    for (int kk = 0; kk < KK; ++kk) {
        unsigned long long g = k[0];
#pragma unroll
        for (int s = 1; s < 64; s <<= 1) {
            unsigned long long o = (unsigned long long)__shfl_xor((long long)g, s, 64);
            if (o < g) g = o;
        }
        bool win = (k[0] == g);
#pragma unroll
        for (int i = 0; i < 15; ++i) k[i] = win ? k[i + 1] : k[i];
        k[15] = win ? ~0ull : k[15];
        if (lane == 0) wl[wv * KK + kk] = g;
    }
    __syncthreads();
    if (wv == 0) {
        unsigned long long mk = (lane < 2 * KK) ? wl[lane] : ~0ull;
        int* orow = idx + (size_t)bn * KK;
        for (int kk = 0; kk < KK; ++kk) {
            unsigned long long g = mk;
#pragma unroll
            for (int s = 1; s < 64; s <<= 1) {
                unsigned long long o = (unsigned long long)__shfl_xor((long long)g, s, 64);
                if (o < g) g = o;
            }
            if (mk == g) mk = ~0ull;
            if (lane == 0) orow[kk] = (int)(g & 2047u);
        }
    }
}

// ---- weight prep, float4-packed per 4-channel chunk (zero-padded to NC4 chunks) ----------
__global__ void k_prepw(const float* __restrict__ W, float4* __restrict__ Wa4,
                        float4* __restrict__ Wd4, int C, int NC4, int Cout) {
    int j = blockIdx.x * blockDim.x + threadIdx.x;
    if (j >= NC4 * Cout) return;
    int chunk = j / Cout, o = j % Cout;
    float wa[4], wd[4];
#pragma unroll
    for (int i = 0; i < 4; ++i) {
        int c = 4 * chunk + i;
        if (c < C) {
            wa[i] = W[(size_t)o * 2 * C + c];
            wd[i] = W[(size_t)o * 2 * C + C + c] - wa[i];
        } else { wa[i] = 0.f; wd[i] = 0.f; }
    }
    Wa4[j] = make_float4(wa[0], wa[1], wa[2], wa[3]);
    Wd4[j] = make_float4(wd[0], wd[1], wd[2], wd[3]);
}

// ---- EdgeConv: P=4 points/block, Mo=2 outputs/thread, NPASS channel passes. --------------
// __launch_bounds__(NTHR, 2) raises the VGPR cap (R13 spilled at 64 VGPR: WRITE_SIZE 193MB).
// Mo=2 halves LDS-read instructions; channel-splitting halves LDS so occupancy stays high.
template <int NC4, int COUT, int P, int NPASS>
__global__ __launch_bounds__(P * COUT / 2, 2)
void k_conv(const float* __restrict__ X, const int* __restrict__ idx,
            const float4* __restrict__ Wa4, const float4* __restrict__ Wd4,
            const float* __restrict__ scale, const float* __restrict__ bias,
            int outoff, float* __restrict__ Xout) {
    constexpr int NCP = NC4 / NPASS;      // chunks per pass (exact: 1,18/2,34/2,50/2)
    constexpr int HALF = COUT / 2;
    constexpr int NTHR = P * HALF;
    int bn0 = blockIdx.x * P;             // P consecutive points, same batch
    int b = bn0 >> 11;                    // NN = 2048
    __shared__ float4 ctr4[P * NCP];
    __shared__ float4 nbr4[P * KK * NCP];
    __shared__ int sIdx[P * KK];
    int tid = threadIdx.x;
    for (int j = tid; j < P * KK; j += NTHR) sIdx[j] = idx[(size_t)bn0 * KK + j];
    __syncthreads();
    int o = tid & (HALF - 1);
    int p = tid / HALF;                   // wave-uniform (HALF=64) or 2-way (HALF=32)
    float bacc0 = 0.f, bacc1 = 0.f;
    float acc0[KK], acc1[KK];
#pragma unroll
    for (int kk = 0; kk < KK; ++kk) { acc0[kk] = 0.f; acc1[kk] = 0.f; }
#pragma unroll
    for (int q = 0; q < NPASS; ++q) {
        int cbase = q * NCP;              // global chunk base for this pass
        // stage ctr chunks
#pragma unroll
        for (int j = tid; j < P * NCP; j += NTHR) {
            int pp = j / NCP, c = j - pp * NCP;
            ctr4[j] = *(const float4*)(X + (size_t)(bn0 + pp) * XS + 4 * (cbase + c));
        }
        // stage nbr chunks
        for (int j = tid; j < P * KK * NCP; j += NTHR) {
            int pk = j / NCP, c = j - pk * NCP;
            nbr4[j] = *(const float4*)(X + (size_t)(b * NN + sIdx[pk]) * XS + 4 * (cbase + c));
        }
        __syncthreads();
        const float4* cp = ctr4 + p * NCP;
        const float4* np = nbr4 + p * KK * NCP;
#pragma unroll 2
        for (int ch = 0; ch < NCP; ++ch) {
            int gch = cbase + ch;
            float4 wa0 = Wa4[(size_t)gch * COUT + o];
            float4 wa1 = Wa4[(size_t)gch * COUT + o + HALF];
            float4 wd0 = Wd4[(size_t)gch * COUT + o];
            float4 wd1 = Wd4[(size_t)gch * COUT + o + HALF];
            float4 cv = cp[ch];
            bacc0 = fmaf(cv.x, wd0.x, bacc0);
            bacc0 = fmaf(cv.y, wd0.y, bacc0);
            bacc0 = fmaf(cv.z, wd0.z, bacc0);
            bacc0 = fmaf(cv.w, wd0.w, bacc0);
            bacc1 = fmaf(cv.x, wd1.x, bacc1);
            bacc1 = fmaf(cv.y, wd1.y, bacc1);
            bacc1 = fmaf(cv.z, wd1.z, bacc1);
            bacc1 = fmaf(cv.w, wd1.w, bacc1);
#pragma unroll
            for (int kk = 0; kk < KK; ++kk) {
                float4 nv = np[kk * NCP + ch];
                acc0[kk] = fmaf(nv.x, wa0.x, acc0[kk]);
                acc0[kk] = fmaf(nv.y, wa0.y, acc0[kk]);
                acc0[kk] = fmaf(nv.z, wa0.z, acc0[kk]);
                acc0[kk] = fmaf(nv.w, wa0.w, acc0[kk]);
                acc1[kk] = fmaf(nv.x, wa1.x, acc1[kk]);
                acc1[kk] = fmaf(nv.y, wa1.y, acc1[kk]);
                acc1[kk] = fmaf(nv.z, wa1.z, acc1[kk]);
                acc1[kk] = fmaf(nv.w, wa1.w, acc1[kk]);
            }
        }
        if (q + 1 < NPASS) __syncthreads();   // before next pass overwrites LDS
    }
    float s0 = scale[o], bi0 = bias[o];
    float s1 = scale[o + HALF], bi1 = bias[o + HALF];
    float mx0 = -INFINITY, mx1 = -INFINITY;
#pragma unroll
    for (int kk = 0; kk < KK; ++kk) {
        mx0 = fmaxf(mx0, lrelu((bacc0 + acc0[kk]) * s0 + bi0));
        mx1 = fmaxf(mx1, lrelu((bacc1 + acc1[kk]) * s1 + bi1));
    }
    float* orow = Xout + (size_t)(bn0 + p) * XS + outoff;
    orow[o] = mx0;
    orow[o + HALF] = mx1;
}

// ---- W5 transpose to [c][o], zero-padded to XS rows (row 323 = 0 so X pad is harmless) ---
__global__ void k_prepw5(const float* __restrict__ W5, float* __restrict__ W5T) {
    int j = blockIdx.x * blockDim.x + threadIdx.x;
    if (j >= XS * 1024) return;
    int c = j / 1024, o = j % 1024;
    W5T[j] = (c < CT) ? W5[(size_t)o * CT + c] : 0.f;
}

__global__ void k_init_gfeat(float* __restrict__ gfeat) {
    int i = blockIdx.x * blockDim.x + threadIdx.x;
    if (i < BB * 1024) gfeat[i] = -INFINITY;
}

// ---- block5: g = lrelu((X . W5^T)*s5+b5), atomic max over n into gfeat -------------------
// float4 LDS broadcasts (8 b128 per 128 FMAs, 1:16) instead of scalar b32.
constexpr int RB = 8;
constexpr int X4S = XS / 4;   // 81 float4 per row
__global__ __launch_bounds__(256) void k_stage5(const float* __restrict__ X,
                                                const float* __restrict__ W5T,
                                                const float* __restrict__ s5,
                                                const float* __restrict__ b5,
                                                float* __restrict__ gfeat) {
    int blk = blockIdx.x;
    int b = blk / (NN / RB);
    int n0 = (blk % (NN / RB)) * RB;
    __shared__ float4 rows4[RB][X4S];
    int tid = threadIdx.x;
    const float4* X4 = (const float4*)X;
    for (int j = tid; j < RB * X4S; j += 256) {
        int r = j / X4S, c = j - r * X4S;
        rows4[r][c] = X4[(size_t)(b * NN + n0 + r) * X4S + c];
    }
    __syncthreads();
    const float4* W5T4 = (const float4*)W5T;   // [XS][256] float4 per row
    float acc[RB][4] = {};
    for (int c4 = 0; c4 < X4S; ++c4) {
        float4 w0 = W5T4[(size_t)(4 * c4 + 0) * 256 + tid];
        float4 w1 = W5T4[(size_t)(4 * c4 + 1) * 256 + tid];
        float4 w2 = W5T4[(size_t)(4 * c4 + 2) * 256 + tid];
        float4 w3 = W5T4[(size_t)(4 * c4 + 3) * 256 + tid];
#pragma unroll
        for (int r = 0; r < RB; ++r) {
            float4 a = rows4[r][c4];
            acc[r][0] = fmaf(a.x, w0.x, acc[r][0]);
            acc[r][1] = fmaf(a.x, w0.y, acc[r][1]);
            acc[r][2] = fmaf(a.x, w0.z, acc[r][2]);
            acc[r][3] = fmaf(a.x, w0.w, acc[r][3]);
            acc[r][0] = fmaf(a.y, w1.x, acc[r][0]);
            acc[r][1] = fmaf(a.y, w1.y, acc[r][1]);
            acc[r][2] = fmaf(a.y, w1.z, acc[r][2]);
            acc[r][3] = fmaf(a.y, w1.w, acc[r][3]);
            acc[r][0] = fmaf(a.z, w2.x, acc[r][0]);
            acc[r][1] = fmaf(a.z, w2.y, acc[r][1]);
            acc[r][2] = fmaf(a.z, w2.z, acc[r][2]);
            acc[r][3] = fmaf(a.z, w2.w, acc[r][3]);
            acc[r][0] = fmaf(a.w, w3.x, acc[r][0]);
            acc[r][1] = fmaf(a.w, w3.y, acc[r][1]);
            acc[r][2] = fmaf(a.w, w3.z, acc[r][2]);
            acc[r][3] = fmaf(a.w, w3.w, acc[r][3]);
        }
    }
    int o0 = tid * 4;
#pragma unroll
    for (int i = 0; i < 4; ++i) {
        int o = o0 + i;
        float s = s5[o], bbv = b5[o];
        float mx = -INFINITY;
#pragma unroll
        for (int r = 0; r < RB; ++r) {
            float v = lrelu(acc[r][i] * s + bbv);
            mx = fmaxf(v, mx);
        }
        atomicMaxF(&gfeat[b * 1024 + o], mx);
    }
}

// ---- FC head -----------------------------------------------------------------------------
__global__ void k_fc1(const float* __restrict__ gfeat, const float* __restrict__ fW1,
                      const float* __restrict__ fb1, const float* __restrict__ fs1,
                      const float* __restrict__ fB1, float* __restrict__ h1) {
    int b = blockIdx.x;
    __shared__ float g[1024];
    int tid = threadIdx.x;
    for (int j = tid; j < 1024; j += 256) g[j] = gfeat[b * 1024 + j];
    __syncthreads();
    for (int o = tid; o < 512; o += 256) {
        const float* wr = fW1 + (size_t)o * 1024;
        float acc = 0.f;
        for (int c = 0; c < 1024; ++c) acc = fmaf(g[c], wr[c], acc);
        h1[b * 512 + o] = lrelu((acc + fb1[o]) * fs1[o] + fB1[o]);
    }
}

__global__ void k_fc2(const float* __restrict__ h1, const float* __restrict__ fW2,
                      const float* __restrict__ fb2, const float* __restrict__ fs2,
                      const float* __restrict__ fB2, float* __restrict__ h2) {
    int b = blockIdx.x;
    __shared__ float g[512];
    int tid = threadIdx.x;
    for (int j = tid; j < 512; j += 256) g[j] = h1[b * 512 + j];
    __syncthreads();
    int o = tid;
    const float* wr = fW2 + (size_t)o * 512;
    float acc = 0.f;
    for (int c = 0; c < 512; ++c) acc = fmaf(g[c], wr[c], acc);
    h2[b * 256 + o] = lrelu((acc + fb2[o]) * fs2[o] + fB2[o]);
}

__global__ void k_fc3(const float* __restrict__ h2, const float* __restrict__ fW3,
                      const float* __restrict__ fb3, float* __restrict__ logits) {
    int b = blockIdx.x;
    __shared__ float g[256];
    int tid = threadIdx.x;
    for (int j = tid; j < 256; j += 64) g[j] = h2[b * 256 + j];
    __syncthreads();
    if (tid < 40) {
        const float* wr = fW3 + (size_t)tid * 256;
        float acc = 0.f;
        for (int c = 0; c < 256; ++c) acc = fmaf(g[c], wr[c], acc);
        logits[b * 40 + tid] = acc + fb3[tid];
    }
}

extern "C" void kernel_launch(void* const* d_in, const int* in_sizes, int n_in,
                              void* d_out, int out_size, void* d_ws, size_t ws_size,
                              hipStream_t stream) {
    const float* x   = (const float*)d_in[0];
    const float* W1  = (const float*)d_in[1];
    const float* s1  = (const float*)d_in[2];
    const float* b1  = (const float*)d_in[3];
    const float* W2  = (const float*)d_in[4];
    const float* s2  = (const float*)d_in[5];
    const float* b2  = (const float*)d_in[6];
    const float* W3  = (const float*)d_in[7];
    const float* s3  = (const float*)d_in[8];
    const float* b3  = (const float*)d_in[9];
    const float* W4  = (const float*)d_in[10];
    const float* s4  = (const float*)d_in[11];
    const float* b4  = (const float*)d_in[12];
    const float* W5  = (const float*)d_in[13];
    const float* s5  = (const float*)d_in[14];
    const float* b5  = (const float*)d_in[15];
    const float* fW1 = (const float*)d_in[16];
    const float* fb1 = (const float*)d_in[17];
    const float* fs1 = (const float*)d_in[18];
    const float* fB1 = (const float*)d_in[19];
    const float* fW2 = (const float*)d_in[20];
    const float* fb2 = (const float*)d_in[21];
    const float* fs2 = (const float*)d_in[22];
    const float* fB2 = (const float*)d_in[23];
    const float* fW3 = (const float*)d_in[24];
    const float* fb3 = (const float*)d_in[25];

    float* out    = (float*)d_out;
    float* logits = out;          // 8*40
    float* gfeat  = out + 320;    // 8*1024

    char* ws = (char*)d_ws;
    size_t off = 0;
    auto alloc = [&](size_t bytes) -> void* {
        void* p = ws + off;
        off += (bytes + 255) & ~(size_t)255;
        return p;
    };
    float* X    = (float*)alloc((size_t)BB * NN * XS * 4);      // 21.2 MB
    float* sq   = (float*)alloc((size_t)BB * NN * 4);
    float* dist = (float*)alloc((size_t)BB * NN * NN * 4);      // 134 MB
    int*   idx  = (int*)  alloc((size_t)BB * NN * KK * 4);
    float4* Wa4 = (float4*)alloc((size_t)50 * 128 * 16);
    float4* Wd4 = (float4*)alloc((size_t)50 * 128 * 16);
    float* W5T  = (float*)alloc((size_t)XS * 1024 * 4);
    float* h1   = (float*)alloc((size_t)BB * 512 * 4);
    float* h2   = (float*)alloc((size_t)BB * 256 * 4);
    (void)ws_size; (void)in_sizes; (void)n_in; (void)out_size;

    k_transpose<<<(BB * 3 * NN + 255) / 256, 256, 0, stream>>>(x, X);

    const int Cs[4]    = {3, 67, 131, 195};
    const int Couts[4] = {64, 64, 64, 128};
    const int offs[4]  = {3, 67, 131, 195};
    const int NC4s[4]  = {1, 18, 34, 50};   // padded chunk counts (NPASS-divisible)
    const float* Ws[4] = {W1, W2, W3, W4};
    const float* ss[4] = {s1, s2, s3, s4};
    const float* bs[4] = {b1, b2, b3, b4};

    constexpr int P = 4;
    constexpr int NT = NN / TM;                 // 16 tiles per dim
    constexpr int NBLK = NT * (NT + 1) / 2;     // 136 lower-triangle tiles
    for (int st = 0; st < 4; ++st) {
        int C = Cs[st], Cout = Couts[st];
        int NC4 = NC4s[st];
        k_sq<<<(BB * NN + 255) / 256, 256, 0, stream>>>(X, sq, C);
        dim3 dg(NBLK, 1, BB);
        k_dist<<<dg, 256, 0, stream>>>(X, sq, dist, C);
        k_select<<<BB * NN, 128, 0, stream>>>(dist, idx);
        k_prepw<<<(NC4 * Cout + 255) / 256, 256, 0, stream>>>(Ws[st], Wa4, Wd4, C, NC4, Cout);
        switch (st) {
            case 0: k_conv<1, 64, P, 1><<<BB * NN / P, P * 32, 0, stream>>>(X, idx, Wa4, Wd4, ss[st], bs[st], offs[st], X); break;
            case 1: k_conv<18, 64, P, 2><<<BB * NN / P, P * 32, 0, stream>>>(X, idx, Wa4, Wd4, ss[st], bs[st], offs[st], X); break;
            case 2: k_conv<34, 64, P, 2><<<BB * NN / P, P * 32, 0, stream>>>(X, idx, Wa4, Wd4, ss[st], bs[st], offs[st], X); break;
            case 3: k_conv<50, 128, P, 2><<<BB * NN / P, P * 64, 0, stream>>>(X, idx, Wa4, Wd4, ss[st], bs[st], offs[st], X); break;
        }
    }

    k_prepw5<<<(XS * 1024 + 255) / 256, 256, 0, stream>>>(W5, W5T);
    k_init_gfeat<<<(BB * 1024 + 255) / 256, 256, 0, stream>>>(gfeat);
    k_stage5<<<BB * (NN / RB), 256, 0, stream>>>(X, W5T, s5, b5, gfeat);
    k_fc1<<<BB, 256, 0, stream>>>(gfeat, fW1, fb1, fs1, fB1, h1);
    k_fc2<<<BB, 256, 0, stream>>>(h1, fW2, fb2, fs2, fB2, h2);
    k_fc3<<<BB, 64, 0, stream>>>(h2, fW3, fb3, logits);
}

// Round 19
// 1779.802 us; speedup vs baseline: 1.0923x; 1.0239x over previous
//
#include <hip/hip_runtime.h>
#include <math.h>

// LDGCNN forward: 4 EdgeConv blocks (knn K=20) + 1x1 conv block + global max pool + 3 FC.
// B=8, N=2048. Feature buffer X: (B, N, XS) rows, columns [pts(3)|f1(64)|f2(64)|f3(64)|f4(128)].
// XS=324 keeps rows 16B-aligned for float4 loads (column 323 is an unused pad).

constexpr int BB = 8;
constexpr int NN = 2048;
constexpr int KK = 20;
constexpr int CT = 323;
constexpr int XS = 324;
constexpr float NEGS = 0.2f;

__device__ __forceinline__ float lrelu(float v) { return v > 0.0f ? v : NEGS * v; }

__device__ __forceinline__ void atomicMaxF(float* addr, float v) {
    if (v >= 0.0f) atomicMax((int*)addr, __float_as_int(v));
    else           atomicMin((unsigned int*)addr, __float_as_uint(v));
}

// ---- fused prep: pack all conv weights + W5T transpose + gfeat init (one launch) ---------
// Wa4/Wd4 packed layout, per-stage chunk-row base (float4 elems): st0@0, st1@64, st2@1216,
// st3@3392; total 9792. Zero-padded chunks make X pad columns harmless.
constexpr int WTOT = 9792;
__global__ void k_prep_all(const float* __restrict__ W1, const float* __restrict__ W2,
                           const float* __restrict__ W3, const float* __restrict__ W4,
                           const float* __restrict__ W5,
                           float4* __restrict__ Wa4, float4* __restrict__ Wd4,
                           float* __restrict__ W5T, float* __restrict__ gfeat) {
    int j = blockIdx.x * blockDim.x + threadIdx.x;
    if (j < WTOT) {
        int base, Cout, C;
        const float* W;
        if (j < 64)        { base = 0;    Cout = 64;  C = 3;   W = W1; }
        else if (j < 1216) { base = 64;   Cout = 64;  C = 67;  W = W2; }
        else if (j < 3392) { base = 1216; Cout = 64;  C = 131; W = W3; }
        else               { base = 3392; Cout = 128; C = 195; W = W4; }
        int local = j - base;
        int chunk = local / Cout, o = local % Cout;
        float wa[4], wd[4];
#pragma unroll
        for (int i = 0; i < 4; ++i) {
            int c = 4 * chunk + i;
            if (c < C) {
                wa[i] = W[(size_t)o * 2 * C + c];
                wd[i] = W[(size_t)o * 2 * C + C + c] - wa[i];
            } else { wa[i] = 0.f; wd[i] = 0.f; }
        }
        Wa4[j] = make_float4(wa[0], wa[1], wa[2], wa[3]);
        Wd4[j] = make_float4(wd[0], wd[1], wd[2], wd[3]);
    } else if (j < WTOT + XS * 1024) {
        int t = j - WTOT;
        int c = t / 1024, o = t % 1024;
        W5T[t] = (c < CT) ? W5[(size_t)o * CT + c] : 0.f;   // row 323 zeroed
    } else if (j < WTOT + XS * 1024 + BB * 1024) {
        gfeat[j - WTOT - XS * 1024] = -INFINITY;
    }
}

// ---- fused transpose + stage-0 norms: x (B,3,N) -> X[:, :, 0:3], sq0 = |p|^2 -------------
__global__ void k_transpose_sq(const float* __restrict__ x, float* __restrict__ X,
                               float* __restrict__ sq) {
    int i = blockIdx.x * blockDim.x + threadIdx.x;   // b*NN + n
    if (i >= BB * NN) return;
    int b = i >> 11, n = i & 2047;
    const float* xb = x + (size_t)b * 3 * NN;
    float vx = xb[n], vy = xb[NN + n], vz = xb[2 * NN + n];
    float* row = X + (size_t)i * XS;
    row[0] = vx; row[1] = vy; row[2] = vz;
    sq[i] = vx * vx + vy * vy + vz * vz;
}

// ---- squared norms over prefix C (stages 1-3) --------------------------------------------
__global__ void k_sq(const float* __restrict__ X, float* __restrict__ sq, int C) {
    int i = blockIdx.x * blockDim.x + threadIdx.x;
    if (i >= BB * NN) return;
    const float* row = X + (size_t)i * XS;
    float s = 0.f;
    for (int c = 0; c < C; ++c) s += row[c] * row[c];
    sq[i] = s;
}

// ---- dist[b][n][m] = max(sq_n + sq_m - 2*dot, 0) — SYMMETRIC: only tiles ti>=tj ----------
// 128x128 tile, 8x8 per thread. Off-diagonal blocks write direct + mirrored (LDS transpose).
constexpr int TM = 128;
__global__ __launch_bounds__(256) void k_dist(const float* __restrict__ X,
                                              const float* __restrict__ sq,
                                              float* __restrict__ dist, int C) {
    int b = blockIdx.z;
    int blk = blockIdx.x;                 // 0..135 -> (ti, tj), ti >= tj
    int ti = (int)((sqrtf(8.0f * blk + 1.0f) - 1.0f) * 0.5f);
    while ((ti + 1) * (ti + 2) / 2 <= blk) ++ti;
    while (ti * (ti + 1) / 2 > blk) --ti;
    int tj = blk - ti * (ti + 1) / 2;
    int m0 = ti * TM;                     // col tile
    int n0 = tj * TM;                     // row tile
    __shared__ float smem[4352];          // 17 KB: staging (16 KB) / transpose T[32][129]
    float* AsB = smem;                    // As[16][TM]
    float* BsB = smem + 2048;             // Bs[16][TM]
    int tid = threadIdx.x;
    int tx = tid & 15;        // cols: m0 + tx + 16*j
    int ty = tid >> 4;        // rows: n0 + ty*8 + i
    float acc[8][8] = {};
    const float* Xb = X + (size_t)b * NN * XS;
    int sr = tid & 127;       // staging row
    int sc0 = (tid >> 7) * 8; // staging channel half (0 or 8)
    for (int c0 = 0; c0 < C; c0 += 16) {
        const float* arow = Xb + (size_t)(n0 + sr) * XS + c0 + sc0;
        const float* brow = Xb + (size_t)(m0 + sr) * XS + c0 + sc0;
        float4 a0 = *(const float4*)(arow);
        float4 a1 = *(const float4*)(arow + 4);
        float4 b0 = *(const float4*)(brow);
        float4 b1 = *(const float4*)(brow + 4);
        float av[8] = {a0.x, a0.y, a0.z, a0.w, a1.x, a1.y, a1.z, a1.w};
        float bv8[8] = {b0.x, b0.y, b0.z, b0.w, b1.x, b1.y, b1.z, b1.w};
#pragma unroll
        for (int i = 0; i < 8; ++i) {
            bool inr = (c0 + sc0 + i) < C;
            AsB[(sc0 + i) * TM + sr] = inr ? av[i] : 0.f;
            BsB[(sc0 + i) * TM + sr] = inr ? bv8[i] : 0.f;
        }
        __syncthreads();
#pragma unroll
        for (int cc = 0; cc < 16; ++cc) {
            float4 a0r = *(const float4*)&AsB[cc * TM + ty * 8];
            float4 a1r = *(const float4*)&AsB[cc * TM + ty * 8 + 4];
            float a[8] = {a0r.x, a0r.y, a0r.z, a0r.w, a1r.x, a1r.y, a1r.z, a1r.w};
            float bv[8];
#pragma unroll
            for (int j = 0; j < 8; ++j) bv[j] = BsB[cc * TM + tx + 16 * j];
#pragma unroll
            for (int i = 0; i < 8; ++i)
#pragma unroll
                for (int j = 0; j < 8; ++j)
                    acc[i][j] = fmaf(a[i], bv[j], acc[i][j]);
        }
        __syncthreads();
    }
    const float* sqb = sq + b * NN;
    float* db = dist + (size_t)b * NN * NN;
    float sm[8];
#pragma unroll
    for (int j = 0; j < 8; ++j) sm[j] = sqb[m0 + tx + 16 * j];
#pragma unroll
    for (int i = 0; i < 8; ++i) {
        int n = n0 + ty * 8 + i;
        float sn = sqb[n];
#pragma unroll
        for (int j = 0; j < 8; ++j) {
            float d = fmaxf(sn + sm[j] - 2.f * acc[i][j], 0.f);
            acc[i][j] = d;                                   // keep for mirror
            db[(size_t)n * NN + m0 + tx + 16 * j] = d;
        }
    }
    if (ti != tj) {
        // mirrored tile: rows m0.., cols n0.. — 4 passes of 32 m-rows via LDS transpose
        float* T = smem;                  // [32][129]
        int r = tid >> 3;                 // 0..31
        int c0 = (tid & 7) * 16;          // 0..112
#pragma unroll
        for (int p = 0; p < 4; ++p) {
            __syncthreads();              // protect staging/previous pass reads
#pragma unroll
            for (int jj = 0; jj < 2; ++jj) {
                int j = 2 * p + jj;       // m_local = 32p + tx + 16jj
#pragma unroll
                for (int i = 0; i < 8; ++i)
                    T[(tx + 16 * jj) * 129 + ty * 8 + i] = acc[i][j];
            }
            __syncthreads();
            float v[16];
#pragma unroll
            for (int k = 0; k < 16; ++k) v[k] = T[r * 129 + c0 + k];
            float* dst = db + (size_t)(m0 + 32 * p + r) * NN + n0 + c0;
#pragma unroll
            for (int k = 0; k < 4; ++k)
                *(float4*)(dst + 4 * k) = make_float4(v[4 * k], v[4 * k + 1],
                                                      v[4 * k + 2], v[4 * k + 3]);
        }
    }
}

// ---- Batcher odd-even mergesort network, N=16, fully unrolled (registers) ----------------
__device__ __forceinline__ void sortnet16(unsigned long long* k) {
#pragma unroll
    for (int p = 1; p < 16; p <<= 1) {
#pragma unroll
        for (int q = p; q >= 1; q >>= 1) {
#pragma unroll
            for (int j = q % p; j + q < 16; j += 2 * q) {
#pragma unroll
                for (int i = 0; i < q; ++i) {
                    int a = j + i, bx = j + i + q;
                    if (bx < 16 && (a / (2 * p)) == (bx / (2 * p))) {
                        unsigned long long ka = k[a], kb = k[bx];
                        bool sw = kb < ka;
                        k[a]  = sw ? kb : ka;
                        k[bx] = sw ? ka : kb;
                    }
                }
            }
        }
    }
}

// ---- top-K smallest per row: key = (bits(d)<<11)|m; ties -> lower m (lax.top_k) ----------
__global__ __launch_bounds__(128) void k_select(const float* __restrict__ dist,
                                                int* __restrict__ idx) {
    int bn = blockIdx.x;   // b*NN + n
    int tid = threadIdx.x;
    int wv = tid >> 6;
    int lane = tid & 63;
    const float* drow = dist + (size_t)bn * NN;
    int m0 = wv * 1024 + lane * 16;
    unsigned long long k[16];
#pragma unroll
    for (int i = 0; i < 4; ++i) {
        float4 v = *(const float4*)(drow + m0 + 4 * i);
        k[4 * i + 0] = ((unsigned long long)__float_as_uint(v.x) << 11) | (unsigned)(m0 + 4 * i + 0);
        k[4 * i + 1] = ((unsigned long long)__float_as_uint(v.y) << 11) | (unsigned)(m0 + 4 * i + 1);
        k[4 * i + 2] = ((unsigned long long)__float_as_uint(v.z) << 11) | (unsigned)(m0 + 4 * i + 2);
        k[4 * i + 3] = ((unsigned long long)__float_as_uint(v.w) << 11) | (unsigned)(m0 + 4 * i + 3);
    }
    sortnet16(k);
    __shared__ unsigned long long wl[2 * KK];
    for (int kk = 0; kk < KK; ++kk) {
        unsigned long long g = k[0];
#pragma unroll
        for (int s = 1; s < 64; s <<= 1) {
            unsigned long long o = (unsigned long long)__shfl_xor((long long)g, s, 64);
            if (o < g) g = o;
        }
        bool win = (k[0] == g);
#pragma unroll
        for (int i = 0; i < 15; ++i) k[i] = win ? k[i + 1] : k[i];
        k[15] = win ? ~0ull : k[15];
        if (lane == 0) wl[wv * KK + kk] = g;
    }
    __syncthreads();
    if (wv == 0) {
        unsigned long long mk = (lane < 2 * KK) ? wl[lane] : ~0ull;
        int* orow = idx + (size_t)bn * KK;
        for (int kk = 0; kk < KK; ++kk) {
            unsigned long long g = mk;
#pragma unroll
            for (int s = 1; s < 64; s <<= 1) {
                unsigned long long o = (unsigned long long)__shfl_xor((long long)g, s, 64);
                if (o < g) g = o;
            }
            if (mk == g) mk = ~0ull;
            if (lane == 0) orow[kk] = (int)(g & 2047u);
        }
    }
}

// ---- EdgeConv: P=4 points/block, Mo=2 outputs/thread, NPASS channel passes. --------------
// __launch_bounds__(NTHR, 2) raises the VGPR cap (R13 spilled at 64 VGPR: WRITE_SIZE 193MB).
// Mo=2 halves LDS-read instructions; channel-splitting halves LDS so occupancy stays high.
template <int NC4, int COUT, int P, int NPASS>
__global__ __launch_bounds__(P * COUT / 2, 2)
void k_conv(const float* __restrict__ X, const int* __restrict__ idx,
            const float4* __restrict__ Wa4, const float4* __restrict__ Wd4,
            const float* __restrict__ scale, const float* __restrict__ bias,
            int outoff, float* __restrict__ Xout) {
    constexpr int NCP = NC4 / NPASS;      // chunks per pass (exact: 1,18/2,34/2,50/2)
    constexpr int HALF = COUT / 2;
    constexpr int NTHR = P * HALF;
    int bn0 = blockIdx.x * P;             // P consecutive points, same batch
    int b = bn0 >> 11;                    // NN = 2048
    __shared__ float4 ctr4[P * NCP];
    __shared__ float4 nbr4[P * KK * NCP];
    __shared__ int sIdx[P * KK];
    int tid = threadIdx.x;
    for (int j = tid; j < P * KK; j += NTHR) sIdx[j] = idx[(size_t)bn0 * KK + j];
    __syncthreads();
    int o = tid & (HALF - 1);
    int p = tid / HALF;                   // wave-uniform (HALF=64) or 2-way (HALF=32)
    float bacc0 = 0.f, bacc1 = 0.f;
    float acc0[KK], acc1[KK];
#pragma unroll
    for (int kk = 0; kk < KK; ++kk) { acc0[kk] = 0.f; acc1[kk] = 0.f; }
#pragma unroll
    for (int q = 0; q < NPASS; ++q) {
        int cbase = q * NCP;              // global chunk base for this pass
        // stage ctr chunks
#pragma unroll
        for (int j = tid; j < P * NCP; j += NTHR) {
            int pp = j / NCP, c = j - pp * NCP;
            ctr4[j] = *(const float4*)(X + (size_t)(bn0 + pp) * XS + 4 * (cbase + c));
        }
        // stage nbr chunks
        for (int j = tid; j < P * KK * NCP; j += NTHR) {
            int pk = j / NCP, c = j - pk * NCP;
            nbr4[j] = *(const float4*)(X + (size_t)(b * NN + sIdx[pk]) * XS + 4 * (cbase + c));
        }
        __syncthreads();
        const float4* cp = ctr4 + p * NCP;
        const float4* np = nbr4 + p * KK * NCP;
#pragma unroll 2
        for (int ch = 0; ch < NCP; ++ch) {
            int gch = cbase + ch;
            float4 wa0 = Wa4[(size_t)gch * COUT + o];
            float4 wa1 = Wa4[(size_t)gch * COUT + o + HALF];
            float4 wd0 = Wd4[(size_t)gch * COUT + o];
            float4 wd1 = Wd4[(size_t)gch * COUT + o + HALF];
            float4 cv = cp[ch];
            bacc0 = fmaf(cv.x, wd0.x, bacc0);
            bacc0 = fmaf(cv.y, wd0.y, bacc0);
            bacc0 = fmaf(cv.z, wd0.z, bacc0);
            bacc0 = fmaf(cv.w, wd0.w, bacc0);
            bacc1 = fmaf(cv.x, wd1.x, bacc1);
            bacc1 = fmaf(cv.y, wd1.y, bacc1);
            bacc1 = fmaf(cv.z, wd1.z, bacc1);
            bacc1 = fmaf(cv.w, wd1.w, bacc1);
#pragma unroll
            for (int kk = 0; kk < KK; ++kk) {
                float4 nv = np[kk * NCP + ch];
                acc0[kk] = fmaf(nv.x, wa0.x, acc0[kk]);
                acc0[kk] = fmaf(nv.y, wa0.y, acc0[kk]);
                acc0[kk] = fmaf(nv.z, wa0.z, acc0[kk]);
                acc0[kk] = fmaf(nv.w, wa0.w, acc0[kk]);
                acc1[kk] = fmaf(nv.x, wa1.x, acc1[kk]);
                acc1[kk] = fmaf(nv.y, wa1.y, acc1[kk]);
                acc1[kk] = fmaf(nv.z, wa1.z, acc1[kk]);
                acc1[kk] = fmaf(nv.w, wa1.w, acc1[kk]);
            }
        }
        if (q + 1 < NPASS) __syncthreads();   // before next pass overwrites LDS
    }
    float s0 = scale[o], bi0 = bias[o];
    float s1 = scale[o + HALF], bi1 = bias[o + HALF];
    float mx0 = -INFINITY, mx1 = -INFINITY;
#pragma unroll
    for (int kk = 0; kk < KK; ++kk) {
        mx0 = fmaxf(mx0, lrelu((bacc0 + acc0[kk]) * s0 + bi0));
        mx1 = fmaxf(mx1, lrelu((bacc1 + acc1[kk]) * s1 + bi1));
    }
    float* orow = Xout + (size_t)(bn0 + p) * XS + outoff;
    orow[o] = mx0;
    orow[o + HALF] = mx1;
}

// ---- block5: g = lrelu((X . W5^T)*s5+b5), atomic max over n into gfeat -------------------
// float4 LDS broadcasts (8 b128 per 128 FMAs, 1:16) instead of scalar b32.
constexpr int RB = 8;
constexpr int X4S = XS / 4;   // 81 float4 per row
__global__ __launch_bounds__(256) void k_stage5(const float* __restrict__ X,
                                                const float* __restrict__ W5T,
                                                const float* __restrict__ s5,
                                                const float* __restrict__ b5,
                                                float* __restrict__ gfeat) {
    int blk = blockIdx.x;
    int b = blk / (NN / RB);
    int n0 = (blk % (NN / RB)) * RB;
    __shared__ float4 rows4[RB][X4S];
    int tid = threadIdx.x;
    const float4* X4 = (const float4*)X;
    for (int j = tid; j < RB * X4S; j += 256) {
        int r = j / X4S, c = j - r * X4S;
        rows4[r][c] = X4[(size_t)(b * NN + n0 + r) * X4S + c];
    }
    __syncthreads();
    const float4* W5T4 = (const float4*)W5T;   // [XS][256] float4 per row
    float acc[RB][4] = {};
    for (int c4 = 0; c4 < X4S; ++c4) {
        float4 w0 = W5T4[(size_t)(4 * c4 + 0) * 256 + tid];
        float4 w1 = W5T4[(size_t)(4 * c4 + 1) * 256 + tid];
        float4 w2 = W5T4[(size_t)(4 * c4 + 2) * 256 + tid];
        float4 w3 = W5T4[(size_t)(4 * c4 + 3) * 256 + tid];
#pragma unroll
        for (int r = 0; r < RB; ++r) {
            float4 a = rows4[r][c4];
            acc[r][0] = fmaf(a.x, w0.x, acc[r][0]);
            acc[r][1] = fmaf(a.x, w0.y, acc[r][1]);
            acc[r][2] = fmaf(a.x, w0.z, acc[r][2]);
            acc[r][3] = fmaf(a.x, w0.w, acc[r][3]);
            acc[r][0] = fmaf(a.y, w1.x, acc[r][0]);
            acc[r][1] = fmaf(a.y, w1.y, acc[r][1]);
            acc[r][2] = fmaf(a.y, w1.z, acc[r][2]);
            acc[r][3] = fmaf(a.y, w1.w, acc[r][3]);
            acc[r][0] = fmaf(a.z, w2.x, acc[r][0]);
            acc[r][1] = fmaf(a.z, w2.y, acc[r][1]);
            acc[r][2] = fmaf(a.z, w2.z, acc[r][2]);
            acc[r][3] = fmaf(a.z, w2.w, acc[r][3]);
            acc[r][0] = fmaf(a.w, w3.x, acc[r][0]);
            acc[r][1] = fmaf(a.w, w3.y, acc[r][1]);
            acc[r][2] = fmaf(a.w, w3.z, acc[r][2]);
            acc[r][3] = fmaf(a.w, w3.w, acc[r][3]);
        }
    }
    int o0 = tid * 4;
#pragma unroll
    for (int i = 0; i < 4; ++i) {
        int o = o0 + i;
        float s = s5[o], bbv = b5[o];
        float mx = -INFINITY;
#pragma unroll
        for (int r = 0; r < RB; ++r) {
            float v = lrelu(acc[r][i] * s + bbv);
            mx = fmaxf(v, mx);
        }
        atomicMaxF(&gfeat[b * 1024 + o], mx);
    }
}

// ---- fused FC head: fc1 -> fc2 -> fc3 per batch row, intermediates in LDS ----------------
__global__ __launch_bounds__(256) void k_fc(const float* __restrict__ gfeat,
                                            const float* __restrict__ fW1, const float* __restrict__ fb1,
                                            const float* __restrict__ fs1, const float* __restrict__ fB1,
                                            const float* __restrict__ fW2, const float* __restrict__ fb2,
                                            const float* __restrict__ fs2, const float* __restrict__ fB2,
                                            const float* __restrict__ fW3, const float* __restrict__ fb3,
                                            float* __restrict__ logits) {
    int b = blockIdx.x;
    __shared__ float g[1024];
    __shared__ float h1s[512];
    __shared__ float h2s[256];
    int tid = threadIdx.x;
    for (int j = tid; j < 1024; j += 256) g[j] = gfeat[b * 1024 + j];
    __syncthreads();
    for (int o = tid; o < 512; o += 256) {
        const float* wr = fW1 + (size_t)o * 1024;
        float acc = 0.f;
        for (int c = 0; c < 1024; ++c) acc = fmaf(g[c], wr[c], acc);
        h1s[o] = lrelu((acc + fb1[o]) * fs1[o] + fB1[o]);
    }
    __syncthreads();
    {
        int o = tid;
        const float* wr = fW2 + (size_t)o * 512;
        float acc = 0.f;
        for (int c = 0; c < 512; ++c) acc = fmaf(h1s[c], wr[c], acc);
        h2s[o] = lrelu((acc + fb2[o]) * fs2[o] + fB2[o]);
    }
    __syncthreads();
    if (tid < 40) {
        const float* wr = fW3 + (size_t)tid * 256;
        float acc = 0.f;
        for (int c = 0; c < 256; ++c) acc = fmaf(h2s[c], wr[c], acc);
        logits[b * 40 + tid] = acc + fb3[tid];
    }
}

extern "C" void kernel_launch(void* const* d_in, const int* in_sizes, int n_in,
                              void* d_out, int out_size, void* d_ws, size_t ws_size,
                              hipStream_t stream) {
    const float* x   = (const float*)d_in[0];
    const float* W1  = (const float*)d_in[1];
    const float* s1  = (const float*)d_in[2];
    const float* b1  = (const float*)d_in[3];
    const float* W2  = (const float*)d_in[4];
    const float* s2  = (const float*)d_in[5];
    const float* b2  = (const float*)d_in[6];
    const float* W3  = (const float*)d_in[7];
    const float* s3  = (const float*)d_in[8];
    const float* b3  = (const float*)d_in[9];
    const float* W4  = (const float*)d_in[10];
    const float* s4  = (const float*)d_in[11];
    const float* b4  = (const float*)d_in[12];
    const float* W5  = (const float*)d_in[13];
    const float* s5  = (const float*)d_in[14];
    const float* b5  = (const float*)d_in[15];
    const float* fW1 = (const float*)d_in[16];
    const float* fb1 = (const float*)d_in[17];
    const float* fs1 = (const float*)d_in[18];
    const float* fB1 = (const float*)d_in[19];
    const float* fW2 = (const float*)d_in[20];
    const float* fb2 = (const float*)d_in[21];
    const float* fs2 = (const float*)d_in[22];
    const float* fB2 = (const float*)d_in[23];
    const float* fW3 = (const float*)d_in[24];
    const float* fb3 = (const float*)d_in[25];

    float* out    = (float*)d_out;
    float* logits = out;          // 8*40
    float* gfeat  = out + 320;    // 8*1024

    char* ws = (char*)d_ws;
    size_t off = 0;
    auto alloc = [&](size_t bytes) -> void* {
        void* p = ws + off;
        off += (bytes + 255) & ~(size_t)255;
        return p;
    };
    float* X    = (float*)alloc((size_t)BB * NN * XS * 4);      // 21.2 MB
    float* sq   = (float*)alloc((size_t)BB * NN * 4);
    float* dist = (float*)alloc((size_t)BB * NN * NN * 4);      // 134 MB
    int*   idx  = (int*)  alloc((size_t)BB * NN * KK * 4);
    float4* Wa4 = (float4*)alloc((size_t)WTOT * 16);
    float4* Wd4 = (float4*)alloc((size_t)WTOT * 16);
    float* W5T  = (float*)alloc((size_t)XS * 1024 * 4);
    (void)ws_size; (void)in_sizes; (void)n_in; (void)out_size;

    // one-shot prep: all conv weight packs + W5T + gfeat init
    int prepTot = WTOT + XS * 1024 + BB * 1024;
    k_prep_all<<<(prepTot + 255) / 256, 256, 0, stream>>>(W1, W2, W3, W4, W5,
                                                          Wa4, Wd4, W5T, gfeat);
    k_transpose_sq<<<(BB * NN + 255) / 256, 256, 0, stream>>>(x, X, sq);

    const int Cs[4]    = {3, 67, 131, 195};
    const int offs[4]  = {3, 67, 131, 195};
    const int WOFF[4]  = {0, 64, 1216, 3392};   // chunk-row base in packed Wa4/Wd4
    const float* ss[4] = {s1, s2, s3, s4};
    const float* bs[4] = {b1, b2, b3, b4};

    constexpr int P = 4;
    constexpr int NT = NN / TM;                 // 16 tiles per dim
    constexpr int NBLK = NT * (NT + 1) / 2;     // 136 lower-triangle tiles
    for (int st = 0; st < 4; ++st) {
        int C = Cs[st];
        if (st > 0)
            k_sq<<<(BB * NN + 255) / 256, 256, 0, stream>>>(X, sq, C);
        dim3 dg(NBLK, 1, BB);
        k_dist<<<dg, 256, 0, stream>>>(X, sq, dist, C);
        k_select<<<BB * NN, 128, 0, stream>>>(dist, idx);
        const float4* wa = Wa4 + WOFF[st];
        const float4* wd = Wd4 + WOFF[st];
        switch (st) {
            case 0: k_conv<1, 64, P, 1><<<BB * NN / P, P * 32, 0, stream>>>(X, idx, wa, wd, ss[st], bs[st], offs[st], X); break;
            case 1: k_conv<18, 64, P, 2><<<BB * NN / P, P * 32, 0, stream>>>(X, idx, wa, wd, ss[st], bs[st], offs[st], X); break;
            case 2: k_conv<34, 64, P, 2><<<BB * NN / P, P * 32, 0, stream>>>(X, idx, wa, wd, ss[st], bs[st], offs[st], X); break;
            case 3: k_conv<50, 128, P, 2><<<BB * NN / P, P * 64, 0, stream>>>(X, idx, wa, wd, ss[st], bs[st], offs[st], X); break;
        }
    }

    k_stage5<<<BB * (NN / RB), 256, 0, stream>>>(X, W5T, s5, b5, gfeat);
    k_fc<<<BB, 256, 0, stream>>>(gfeat, fW1, fb1, fs1, fB1,
                                 fW2, fb2, fs2, fB2, fW3, fb3, logits);
}

// Round 20
// 1748.420 us; speedup vs baseline: 1.1119x; 1.0179x over previous
//
#include <hip/hip_runtime.h>
#include <math.h>

// LDGCNN forward: 4 EdgeConv blocks (knn K=20) + 1x1 conv block + global max pool + 3 FC.
// B=8, N=2048. Feature buffer X: (B, N, XS) rows, columns [pts(3)|f1(64)|f2(64)|f3(64)|f4(128)].
// XS=324 keeps rows 16B-aligned for float4 loads (column 323 is an unused pad).

constexpr int BB = 8;
constexpr int NN = 2048;
constexpr int KK = 20;
constexpr int CT = 323;
constexpr int XS = 324;
constexpr float NEGS = 0.2f;

__device__ __forceinline__ float lrelu(float v) { return v > 0.0f ? v : NEGS * v; }

__device__ __forceinline__ void atomicMaxF(float* addr, float v) {
    if (v >= 0.0f) atomicMax((int*)addr, __float_as_int(v));
    else           atomicMin((unsigned int*)addr, __float_as_uint(v));
}

// ---- fused prep: weight packs + W5T transpose + gfeat init + transpose/sq0 (one launch) --
// Wa4/Wd4 packed layout, per-stage chunk-row base (float4 elems): st0@0, st1@64, st2@1216,
// st3@3392; total 9792. Zero-padded chunks make X pad columns harmless.
constexpr int WTOT = 9792;
__global__ void k_prep_all(const float* __restrict__ W1, const float* __restrict__ W2,
                           const float* __restrict__ W3, const float* __restrict__ W4,
                           const float* __restrict__ W5, const float* __restrict__ x,
                           float4* __restrict__ Wa4, float4* __restrict__ Wd4,
                           float* __restrict__ W5T, float* __restrict__ gfeat,
                           float* __restrict__ X, float* __restrict__ sq) {
    int j = blockIdx.x * blockDim.x + threadIdx.x;
    if (j < WTOT) {
        int base, Cout, C;
        const float* W;
        if (j < 64)        { base = 0;    Cout = 64;  C = 3;   W = W1; }
        else if (j < 1216) { base = 64;   Cout = 64;  C = 67;  W = W2; }
        else if (j < 3392) { base = 1216; Cout = 64;  C = 131; W = W3; }
        else               { base = 3392; Cout = 128; C = 195; W = W4; }
        int local = j - base;
        int chunk = local / Cout, o = local % Cout;
        float wa[4], wd[4];
#pragma unroll
        for (int i = 0; i < 4; ++i) {
            int c = 4 * chunk + i;
            if (c < C) {
                wa[i] = W[(size_t)o * 2 * C + c];
                wd[i] = W[(size_t)o * 2 * C + C + c] - wa[i];
            } else { wa[i] = 0.f; wd[i] = 0.f; }
        }
        Wa4[j] = make_float4(wa[0], wa[1], wa[2], wa[3]);
        Wd4[j] = make_float4(wd[0], wd[1], wd[2], wd[3]);
    } else if (j < WTOT + XS * 1024) {
        int t = j - WTOT;
        int c = t / 1024, o = t % 1024;
        W5T[t] = (c < CT) ? W5[(size_t)o * CT + c] : 0.f;   // row 323 zeroed
    } else if (j < WTOT + XS * 1024 + BB * 1024) {
        gfeat[j - WTOT - XS * 1024] = -INFINITY;
    } else if (j < WTOT + XS * 1024 + BB * 1024 + BB * NN) {
        int i = j - WTOT - XS * 1024 - BB * 1024;            // b*NN + n
        int b = i >> 11, n = i & 2047;
        const float* xb = x + (size_t)b * 3 * NN;
        float vx = xb[n], vy = xb[NN + n], vz = xb[2 * NN + n];
        float* row = X + (size_t)i * XS;
        row[0] = vx; row[1] = vy; row[2] = vz;
        sq[i] = vx * vx + vy * vy + vz * vz;
    }
}

// ---- dist[b][n][m] = max(sq_n + sq_m - 2*dot, 0) — SYMMETRIC: only tiles ti>=tj ----------
// 128x128 tile, 8x8 per thread. Off-diagonal blocks write direct + mirrored (LDS transpose).
constexpr int TM = 128;
__global__ __launch_bounds__(256) void k_dist(const float* __restrict__ X,
                                              const float* __restrict__ sq,
                                              float* __restrict__ dist, int C) {
    int b = blockIdx.z;
    int blk = blockIdx.x;                 // 0..135 -> (ti, tj), ti >= tj
    int ti = (int)((sqrtf(8.0f * blk + 1.0f) - 1.0f) * 0.5f);
    while ((ti + 1) * (ti + 2) / 2 <= blk) ++ti;
    while (ti * (ti + 1) / 2 > blk) --ti;
    int tj = blk - ti * (ti + 1) / 2;
    int m0 = ti * TM;                     // col tile
    int n0 = tj * TM;                     // row tile
    __shared__ float smem[4352];          // 17 KB: staging (16 KB) / transpose T[32][129]
    float* AsB = smem;                    // As[16][TM]
    float* BsB = smem + 2048;             // Bs[16][TM]
    int tid = threadIdx.x;
    int tx = tid & 15;        // cols: m0 + tx + 16*j
    int ty = tid >> 4;        // rows: n0 + ty*8 + i
    float acc[8][8] = {};
    const float* Xb = X + (size_t)b * NN * XS;
    int sr = tid & 127;       // staging row
    int sc0 = (tid >> 7) * 8; // staging channel half (0 or 8)
    for (int c0 = 0; c0 < C; c0 += 16) {
        const float* arow = Xb + (size_t)(n0 + sr) * XS + c0 + sc0;
        const float* brow = Xb + (size_t)(m0 + sr) * XS + c0 + sc0;
        float4 a0 = *(const float4*)(arow);
        float4 a1 = *(const float4*)(arow + 4);
        float4 b0 = *(const float4*)(brow);
        float4 b1 = *(const float4*)(brow + 4);
        float av[8] = {a0.x, a0.y, a0.z, a0.w, a1.x, a1.y, a1.z, a1.w};
        float bv8[8] = {b0.x, b0.y, b0.z, b0.w, b1.x, b1.y, b1.z, b1.w};
#pragma unroll
        for (int i = 0; i < 8; ++i) {
            bool inr = (c0 + sc0 + i) < C;
            AsB[(sc0 + i) * TM + sr] = inr ? av[i] : 0.f;
            BsB[(sc0 + i) * TM + sr] = inr ? bv8[i] : 0.f;
        }
        __syncthreads();
#pragma unroll
        for (int cc = 0; cc < 16; ++cc) {
            float4 a0r = *(const float4*)&AsB[cc * TM + ty * 8];
            float4 a1r = *(const float4*)&AsB[cc * TM + ty * 8 + 4];
            float a[8] = {a0r.x, a0r.y, a0r.z, a0r.w, a1r.x, a1r.y, a1r.z, a1r.w};
            float bv[8];
#pragma unroll
            for (int j = 0; j < 8; ++j) bv[j] = BsB[cc * TM + tx + 16 * j];
#pragma unroll
            for (int i = 0; i < 8; ++i)
#pragma unroll
                for (int j = 0; j < 8; ++j)
                    acc[i][j] = fmaf(a[i], bv[j], acc[i][j]);
        }
        __syncthreads();
    }
    const float* sqb = sq + b * NN;
    float* db = dist + (size_t)b * NN * NN;
    float sm[8];
#pragma unroll
    for (int j = 0; j < 8; ++j) sm[j] = sqb[m0 + tx + 16 * j];
#pragma unroll
    for (int i = 0; i < 8; ++i) {
        int n = n0 + ty * 8 + i;
        float sn = sqb[n];
#pragma unroll
        for (int j = 0; j < 8; ++j) {
            float d = fmaxf(sn + sm[j] - 2.f * acc[i][j], 0.f);
            acc[i][j] = d;                                   // keep for mirror
            db[(size_t)n * NN + m0 + tx + 16 * j] = d;
        }
    }
    if (ti != tj) {
        // mirrored tile: rows m0.., cols n0.. — 4 passes of 32 m-rows via LDS transpose
        float* T = smem;                  // [32][129]
        int r = tid >> 3;                 // 0..31
        int c0 = (tid & 7) * 16;          // 0..112
#pragma unroll
        for (int p = 0; p < 4; ++p) {
            __syncthreads();              // protect staging/previous pass reads
#pragma unroll
            for (int jj = 0; jj < 2; ++jj) {
                int j = 2 * p + jj;       // m_local = 32p + tx + 16jj
#pragma unroll
                for (int i = 0; i < 8; ++i)
                    T[(tx + 16 * jj) * 129 + ty * 8 + i] = acc[i][j];
            }
            __syncthreads();
            float v[16];
#pragma unroll
            for (int k = 0; k < 16; ++k) v[k] = T[r * 129 + c0 + k];
            float* dst = db + (size_t)(m0 + 32 * p + r) * NN + n0 + c0;
#pragma unroll
            for (int k = 0; k < 4; ++k)
                *(float4*)(dst + 4 * k) = make_float4(v[4 * k], v[4 * k + 1],
                                                      v[4 * k + 2], v[4 * k + 3]);
        }
    }
}

// ---- Batcher odd-even mergesort network, N=16, fully unrolled (registers) ----------------
__device__ __forceinline__ void sortnet16(unsigned long long* k) {
#pragma unroll
    for (int p = 1; p < 16; p <<= 1) {
#pragma unroll
        for (int q = p; q >= 1; q >>= 1) {
#pragma unroll
            for (int j = q % p; j + q < 16; j += 2 * q) {
#pragma unroll
                for (int i = 0; i < q; ++i) {
                    int a = j + i, bx = j + i + q;
                    if (bx < 16 && (a / (2 * p)) == (bx / (2 * p))) {
                        unsigned long long ka = k[a], kb = k[bx];
                        bool sw = kb < ka;
                        k[a]  = sw ? kb : ka;
                        k[bx] = sw ? ka : kb;
                    }
                }
            }
        }
    }
}

// ---- top-K smallest per row: key = (bits(d)<<11)|m; ties -> lower m (lax.top_k) ----------
__global__ __launch_bounds__(128) void k_select(const float* __restrict__ dist,
                                                int* __restrict__ idx) {
    int bn = blockIdx.x;   // b*NN + n
    int tid = threadIdx.x;
    int wv = tid >> 6;
    int lane = tid & 63;
    const float* drow = dist + (size_t)bn * NN;
    int m0 = wv * 1024 + lane * 16;
    unsigned long long k[16];
#pragma unroll
    for (int i = 0; i < 4; ++i) {
        float4 v = *(const float4*)(drow + m0 + 4 * i);
        k[4 * i + 0] = ((unsigned long long)__float_as_uint(v.x) << 11) | (unsigned)(m0 + 4 * i + 0);
        k[4 * i + 1] = ((unsigned long long)__float_as_uint(v.y) << 11) | (unsigned)(m0 + 4 * i + 1);
        k[4 * i + 2] = ((unsigned long long)__float_as_uint(v.z) << 11) | (unsigned)(m0 + 4 * i + 2);
        k[4 * i + 3] = ((unsigned long long)__float_as_uint(v.w) << 11) | (unsigned)(m0 + 4 * i + 3);
    }
    sortnet16(k);
    __shared__ unsigned long long wl[2 * KK];
    for (int kk = 0; kk < KK; ++kk) {
        unsigned long long g = k[0];
#pragma unroll
        for (int s = 1; s < 64; s <<= 1) {
            unsigned long long o = (unsigned long long)__shfl_xor((long long)g, s, 64);
            if (o < g) g = o;
        }
        bool win = (k[0] == g);
#pragma unroll
        for (int i = 0; i < 15; ++i) k[i] = win ? k[i + 1] : k[i];
        k[15] = win ? ~0ull : k[15];
        if (lane == 0) wl[wv * KK + kk] = g;
    }
    __syncthreads();
    if (wv == 0) {
        unsigned long long mk = (lane < 2 * KK) ? wl[lane] : ~0ull;
        int* orow = idx + (size_t)bn * KK;
        for (int kk = 0; kk < KK; ++kk) {
            unsigned long long g = mk;
#pragma unroll
            for (int s = 1; s < 64; s <<= 1) {
                unsigned long long o = (unsigned long long)__shfl_xor((long long)g, s, 64);
                if (o < g) g = o;
            }
            if (mk == g) mk = ~0ull;
            if (lane == 0) orow[kk] = (int)(g & 2047u);
        }
    }
}

// ---- EdgeConv: P=4 points/block, Mo=2 outputs/thread, NPASS channel passes. --------------
// __launch_bounds__(NTHR, 2) raises the VGPR cap (R13 spilled at 64 VGPR: WRITE_SIZE 193MB).
// Mo=2 halves LDS-read instructions; channel-splitting halves LDS so occupancy stays high.
// Epilogue also updates sq[bn] += sum(new channels^2) via width-HALF shuffle reduction,
// producing the prefix norms the NEXT stage's dist needs (replaces the k_sq kernel).
template <int NC4, int COUT, int P, int NPASS>
__global__ __launch_bounds__(P * COUT / 2, 2)
void k_conv(const float* __restrict__ X, const int* __restrict__ idx,
            const float4* __restrict__ Wa4, const float4* __restrict__ Wd4,
            const float* __restrict__ scale, const float* __restrict__ bias,
            int outoff, float* __restrict__ Xout, float* __restrict__ sq) {
    constexpr int NCP = NC4 / NPASS;      // chunks per pass (exact: 1,18/2,34/2,50/2)
    constexpr int HALF = COUT / 2;
    constexpr int NTHR = P * HALF;
    int bn0 = blockIdx.x * P;             // P consecutive points, same batch
    int b = bn0 >> 11;                    // NN = 2048
    __shared__ float4 ctr4[P * NCP];
    __shared__ float4 nbr4[P * KK * NCP];
    __shared__ int sIdx[P * KK];
    int tid = threadIdx.x;
    for (int j = tid; j < P * KK; j += NTHR) sIdx[j] = idx[(size_t)bn0 * KK + j];
    __syncthreads();
    int o = tid & (HALF - 1);
    int p = tid / HALF;                   // wave-uniform (HALF=64) or 2-way (HALF=32)
    float bacc0 = 0.f, bacc1 = 0.f;
    float acc0[KK], acc1[KK];
#pragma unroll
    for (int kk = 0; kk < KK; ++kk) { acc0[kk] = 0.f; acc1[kk] = 0.f; }
#pragma unroll
    for (int q = 0; q < NPASS; ++q) {
        int cbase = q * NCP;              // global chunk base for this pass
        // stage ctr chunks
#pragma unroll
        for (int j = tid; j < P * NCP; j += NTHR) {
            int pp = j / NCP, c = j - pp * NCP;
            ctr4[j] = *(const float4*)(X + (size_t)(bn0 + pp) * XS + 4 * (cbase + c));
        }
        // stage nbr chunks
        for (int j = tid; j < P * KK * NCP; j += NTHR) {
            int pk = j / NCP, c = j - pk * NCP;
            nbr4[j] = *(const float4*)(X + (size_t)(b * NN + sIdx[pk]) * XS + 4 * (cbase + c));
        }
        __syncthreads();
        const float4* cp = ctr4 + p * NCP;
        const float4* np = nbr4 + p * KK * NCP;
#pragma unroll 2
        for (int ch = 0; ch < NCP; ++ch) {
            int gch = cbase + ch;
            float4 wa0 = Wa4[(size_t)gch * COUT + o];
            float4 wa1 = Wa4[(size_t)gch * COUT + o + HALF];
            float4 wd0 = Wd4[(size_t)gch * COUT + o];
            float4 wd1 = Wd4[(size_t)gch * COUT + o + HALF];
            float4 cv = cp[ch];
            bacc0 = fmaf(cv.x, wd0.x, bacc0);
            bacc0 = fmaf(cv.y, wd0.y, bacc0);
            bacc0 = fmaf(cv.z, wd0.z, bacc0);
            bacc0 = fmaf(cv.w, wd0.w, bacc0);
            bacc1 = fmaf(cv.x, wd1.x, bacc1);
            bacc1 = fmaf(cv.y, wd1.y, bacc1);
            bacc1 = fmaf(cv.z, wd1.z, bacc1);
            bacc1 = fmaf(cv.w, wd1.w, bacc1);
#pragma unroll
            for (int kk = 0; kk < KK; ++kk) {
                float4 nv = np[kk * NCP + ch];
                acc0[kk] = fmaf(nv.x, wa0.x, acc0[kk]);
                acc0[kk] = fmaf(nv.y, wa0.y, acc0[kk]);
                acc0[kk] = fmaf(nv.z, wa0.z, acc0[kk]);
                acc0[kk] = fmaf(nv.w, wa0.w, acc0[kk]);
                acc1[kk] = fmaf(nv.x, wa1.x, acc1[kk]);
                acc1[kk] = fmaf(nv.y, wa1.y, acc1[kk]);
                acc1[kk] = fmaf(nv.z, wa1.z, acc1[kk]);
                acc1[kk] = fmaf(nv.w, wa1.w, acc1[kk]);
            }
        }
        if (q + 1 < NPASS) __syncthreads();   // before next pass overwrites LDS
    }
    float s0 = scale[o], bi0 = bias[o];
    float s1 = scale[o + HALF], bi1 = bias[o + HALF];
    float mx0 = -INFINITY, mx1 = -INFINITY;
#pragma unroll
    for (int kk = 0; kk < KK; ++kk) {
        mx0 = fmaxf(mx0, lrelu((bacc0 + acc0[kk]) * s0 + bi0));
        mx1 = fmaxf(mx1, lrelu((bacc1 + acc1[kk]) * s1 + bi1));
    }
    float* orow = Xout + (size_t)(bn0 + p) * XS + outoff;
    orow[o] = mx0;
    orow[o + HALF] = mx1;
    // fused sq update for next stage: sq += sum over new channels of value^2
    float v = mx0 * mx0 + mx1 * mx1;
#pragma unroll
    for (int s = 1; s < HALF; s <<= 1) v += __shfl_xor(v, s, HALF);
    if (o == 0) sq[bn0 + p] += v;
}

// ---- block5: g = lrelu((X . W5^T)*s5+b5), atomic max over n into gfeat -------------------
// float4 LDS broadcasts (8 b128 per 128 FMAs, 1:16) instead of scalar b32.
constexpr int RB = 8;
constexpr int X4S = XS / 4;   // 81 float4 per row
__global__ __launch_bounds__(256) void k_stage5(const float* __restrict__ X,
                                                const float* __restrict__ W5T,
                                                const float* __restrict__ s5,
                                                const float* __restrict__ b5,
                                                float* __restrict__ gfeat) {
    int blk = blockIdx.x;
    int b = blk / (NN / RB);
    int n0 = (blk % (NN / RB)) * RB;
    __shared__ float4 rows4[RB][X4S];
    int tid = threadIdx.x;
    const float4* X4 = (const float4*)X;
    for (int j = tid; j < RB * X4S; j += 256) {
        int r = j / X4S, c = j - r * X4S;
        rows4[r][c] = X4[(size_t)(b * NN + n0 + r) * X4S + c];
    }
    __syncthreads();
    const float4* W5T4 = (const float4*)W5T;   // [XS][256] float4 per row
    float acc[RB][4] = {};
    for (int c4 = 0; c4 < X4S; ++c4) {
        float4 w0 = W5T4[(size_t)(4 * c4 + 0) * 256 + tid];
        float4 w1 = W5T4[(size_t)(4 * c4 + 1) * 256 + tid];
        float4 w2 = W5T4[(size_t)(4 * c4 + 2) * 256 + tid];
        float4 w3 = W5T4[(size_t)(4 * c4 + 3) * 256 + tid];
#pragma unroll
        for (int r = 0; r < RB; ++r) {
            float4 a = rows4[r][c4];
            acc[r][0] = fmaf(a.x, w0.x, acc[r][0]);
            acc[r][1] = fmaf(a.x, w0.y, acc[r][1]);
            acc[r][2] = fmaf(a.x, w0.z, acc[r][2]);
            acc[r][3] = fmaf(a.x, w0.w, acc[r][3]);
            acc[r][0] = fmaf(a.y, w1.x, acc[r][0]);
            acc[r][1] = fmaf(a.y, w1.y, acc[r][1]);
            acc[r][2] = fmaf(a.y, w1.z, acc[r][2]);
            acc[r][3] = fmaf(a.y, w1.w, acc[r][3]);
            acc[r][0] = fmaf(a.z, w2.x, acc[r][0]);
            acc[r][1] = fmaf(a.z, w2.y, acc[r][1]);
            acc[r][2] = fmaf(a.z, w2.z, acc[r][2]);
            acc[r][3] = fmaf(a.z, w2.w, acc[r][3]);
            acc[r][0] = fmaf(a.w, w3.x, acc[r][0]);
            acc[r][1] = fmaf(a.w, w3.y, acc[r][1]);
            acc[r][2] = fmaf(a.w, w3.z, acc[r][2]);
            acc[r][3] = fmaf(a.w, w3.w, acc[r][3]);
        }
    }
    int o0 = tid * 4;
#pragma unroll
    for (int i = 0; i < 4; ++i) {
        int o = o0 + i;
        float s = s5[o], bbv = b5[o];
        float mx = -INFINITY;
#pragma unroll
        for (int r = 0; r < RB; ++r) {
            float v = lrelu(acc[r][i] * s + bbv);
            mx = fmaxf(v, mx);
        }
        atomicMaxF(&gfeat[b * 1024 + o], mx);
    }
}

// ---- fused FC head: fc1 -> fc2 -> fc3 per batch row, intermediates in LDS ----------------
__global__ __launch_bounds__(256) void k_fc(const float* __restrict__ gfeat,
                                            const float* __restrict__ fW1, const float* __restrict__ fb1,
                                            const float* __restrict__ fs1, const float* __restrict__ fB1,
                                            const float* __restrict__ fW2, const float* __restrict__ fb2,
                                            const float* __restrict__ fs2, const float* __restrict__ fB2,
                                            const float* __restrict__ fW3, const float* __restrict__ fb3,
                                            float* __restrict__ logits) {
    int b = blockIdx.x;
    __shared__ float g[1024];
    __shared__ float h1s[512];
    __shared__ float h2s[256];
    int tid = threadIdx.x;
    for (int j = tid; j < 1024; j += 256) g[j] = gfeat[b * 1024 + j];
    __syncthreads();
    for (int o = tid; o < 512; o += 256) {
        const float* wr = fW1 + (size_t)o * 1024;
        float acc = 0.f;
        for (int c = 0; c < 1024; ++c) acc = fmaf(g[c], wr[c], acc);
        h1s[o] = lrelu((acc + fb1[o]) * fs1[o] + fB1[o]);
    }
    __syncthreads();
    {
        int o = tid;
        const float* wr = fW2 + (size_t)o * 512;
        float acc = 0.f;
        for (int c = 0; c < 512; ++c) acc = fmaf(h1s[c], wr[c], acc);
        h2s[o] = lrelu((acc + fb2[o]) * fs2[o] + fB2[o]);
    }
    __syncthreads();
    if (tid < 40) {
        const float* wr = fW3 + (size_t)tid * 256;
        float acc = 0.f;
        for (int c = 0; c < 256; ++c) acc = fmaf(h2s[c], wr[c], acc);
        logits[b * 40 + tid] = acc + fb3[tid];
    }
}

extern "C" void kernel_launch(void* const* d_in, const int* in_sizes, int n_in,
                              void* d_out, int out_size, void* d_ws, size_t ws_size,
                              hipStream_t stream) {
    const float* x   = (const float*)d_in[0];
    const float* W1  = (const float*)d_in[1];
    const float* s1  = (const float*)d_in[2];
    const float* b1  = (const float*)d_in[3];
    const float* W2  = (const float*)d_in[4];
    const float* s2  = (const float*)d_in[5];
    const float* b2  = (const float*)d_in[6];
    const float* W3  = (const float*)d_in[7];
    const float* s3  = (const float*)d_in[8];
    const float* b3  = (const float*)d_in[9];
    const float* W4  = (const float*)d_in[10];
    const float* s4  = (const float*)d_in[11];
    const float* b4  = (const float*)d_in[12];
    const float* W5  = (const float*)d_in[13];
    const float* s5  = (const float*)d_in[14];
    const float* b5  = (const float*)d_in[15];
    const float* fW1 = (const float*)d_in[16];
    const float* fb1 = (const float*)d_in[17];
    const float* fs1 = (const float*)d_in[18];
    const float* fB1 = (const float*)d_in[19];
    const float* fW2 = (const float*)d_in[20];
    const float* fb2 = (const float*)d_in[21];
    const float* fs2 = (const float*)d_in[22];
    const float* fB2 = (const float*)d_in[23];
    const float* fW3 = (const float*)d_in[24];
    const float* fb3 = (const float*)d_in[25];

    float* out    = (float*)d_out;
    float* logits = out;          // 8*40
    float* gfeat  = out + 320;    // 8*1024

    char* ws = (char*)d_ws;
    size_t off = 0;
    auto alloc = [&](size_t bytes) -> void* {
        void* p = ws + off;
        off += (bytes + 255) & ~(size_t)255;
        return p;
    };
    float* X    = (float*)alloc((size_t)BB * NN * XS * 4);      // 21.2 MB
    float* sq   = (float*)alloc((size_t)BB * NN * 4);
    float* dist = (float*)alloc((size_t)BB * NN * NN * 4);      // 134 MB
    int*   idx  = (int*)  alloc((size_t)BB * NN * KK * 4);
    float4* Wa4 = (float4*)alloc((size_t)WTOT * 16);
    float4* Wd4 = (float4*)alloc((size_t)WTOT * 16);
    float* W5T  = (float*)alloc((size_t)XS * 1024 * 4);
    (void)ws_size; (void)in_sizes; (void)n_in; (void)out_size;

    // one-shot prep: weight packs + W5T + gfeat init + transpose/sq0
    int prepTot = WTOT + XS * 1024 + BB * 1024 + BB * NN;
    k_prep_all<<<(prepTot + 255) / 256, 256, 0, stream>>>(W1, W2, W3, W4, W5, x,
                                                          Wa4, Wd4, W5T, gfeat, X, sq);

    const int Cs[4]    = {3, 67, 131, 195};
    const int offs[4]  = {3, 67, 131, 195};
    const int WOFF[4]  = {0, 64, 1216, 3392};   // chunk-row base in packed Wa4/Wd4
    const float* ss[4] = {s1, s2, s3, s4};
    const float* bs[4] = {b1, b2, b3, b4};

    constexpr int P = 4;
    constexpr int NT = NN / TM;                 // 16 tiles per dim
    constexpr int NBLK = NT * (NT + 1) / 2;     // 136 lower-triangle tiles
    for (int st = 0; st < 4; ++st) {
        int C = Cs[st];
        dim3 dg(NBLK, 1, BB);
        k_dist<<<dg, 256, 0, stream>>>(X, sq, dist, C);
        k_select<<<BB * NN, 128, 0, stream>>>(dist, idx);
        const float4* wa = Wa4 + WOFF[st];
        const float4* wd = Wd4 + WOFF[st];
        switch (st) {
            case 0: k_conv<1, 64, P, 1><<<BB * NN / P, P * 32, 0, stream>>>(X, idx, wa, wd, ss[st], bs[st], offs[st], X, sq); break;
            case 1: k_conv<18, 64, P, 2><<<BB * NN / P, P * 32, 0, stream>>>(X, idx, wa, wd, ss[st], bs[st], offs[st], X, sq); break;
            case 2: k_conv<34, 64, P, 2><<<BB * NN / P, P * 32, 0, stream>>>(X, idx, wa, wd, ss[st], bs[st], offs[st], X, sq); break;
            case 3: k_conv<50, 128, P, 2><<<BB * NN / P, P * 64, 0, stream>>>(X, idx, wa, wd, ss[st], bs[st], offs[st], X, sq); break;
        }
    }

    k_stage5<<<BB * (NN / RB), 256, 0, stream>>>(X, W5T, s5, b5, gfeat);
    k_fc<<<BB, 256, 0, stream>>>(gfeat, fW1, fb1, fs1, fB1,
                                 fW2, fb2, fs2, fB2, fW3, fb3, logits);
}